// Round 6
// baseline (363.254 us; speedup 1.0000x reference)
//
#include <hip/hip_runtime.h>

typedef unsigned short u16;
typedef unsigned long long u64;
typedef __attribute__((ext_vector_type(8))) short bf16x8;
typedef __attribute__((ext_vector_type(4))) float f32x4;

// async global->LDS, 16B per lane. LDS dest must be wave-uniform base + lane*16.
#define GLOAD_LDS(gptr, lptr)                                                            \
  __builtin_amdgcn_global_load_lds(                                                      \
      (const __attribute__((address_space(1))) unsigned int*)(gptr),                     \
      (__attribute__((address_space(3))) unsigned int*)(lptr), 16, 0, 0)

__device__ __forceinline__ float bf2f(u16 u) {
  union { unsigned v; float f; } x; x.v = ((unsigned)u) << 16; return x.f;
}
__device__ __forceinline__ u16 f2bf(float f) {
  union { float f; unsigned v; } x; x.f = f;
  unsigned r = x.v + 0x7FFFu + ((x.v >> 16) & 1u);
  return (u16)(r >> 16);
}

#define MFMA16(a, b, c) __builtin_amdgcn_mfma_f32_16x16x32_bf16((a), (b), (c), 0, 0, 0)

// ---------------------------------------------------------------------------
// Dtype probe (R5-verified: inputs are fp32; probe kept for robustness).
// ---------------------------------------------------------------------------
__global__ __launch_bounds__(256) void detect_dtype(const unsigned* __restrict__ x,
                                                    int* __restrict__ flag) {
  __shared__ int cnt;
  if (threadIdx.x == 0) cnt = 0;
  __syncthreads();
  int local = 0;
  for (int i = threadIdx.x; i < 2048; i += 256) {
    unsigned w = x[i];
    int e = (w >> 7) & 0xFF;
    if (e >= 118 && e <= 130) local++;
  }
  atomicAdd(&cnt, local);
  __syncthreads();
  if (threadIdx.x == 0) *flag = (cnt > 1024) ? 1 : 0;
}

__global__ __launch_bounds__(256) void cvt_bf16(const void* __restrict__ src,
                                                u16* __restrict__ dst, int n8,
                                                const int* __restrict__ flag) {
  int i = blockIdx.x * 256 + threadIdx.x;
  if (i >= n8) return;
  if (*flag) {
    ((ulonglong2*)dst)[i] = ((const ulonglong2*)src)[i];
  } else {
    const float* s = (const float*)src + (size_t)i * 8;
    u16 v[8];
#pragma unroll
    for (int j = 0; j < 8; ++j) v[j] = f2bf(s[j]);
    *(ulonglong2*)(dst + (size_t)i * 8) = *(ulonglong2*)v;
  }
}

// cos+sin tables converted in one launch (two tiny launches fused). [R4-verified]
__global__ __launch_bounds__(256) void cvt_bf16_2(const void* __restrict__ src0,
                                                  const void* __restrict__ src1,
                                                  u16* __restrict__ dst0,
                                                  u16* __restrict__ dst1, int n8,
                                                  const int* __restrict__ flag) {
  int half = gridDim.x >> 1;
  const void* src = (blockIdx.x < half) ? src0 : src1;
  u16* dst = (blockIdx.x < half) ? dst0 : dst1;
  int i = (blockIdx.x < half ? blockIdx.x : blockIdx.x - half) * 256 + threadIdx.x;
  if (i >= n8) return;
  if (*flag) {
    ((ulonglong2*)dst)[i] = ((const ulonglong2*)src)[i];
  } else {
    const float* s = (const float*)src + (size_t)i * 8;
    u16 v[8];
#pragma unroll
    for (int j = 0; j < 8; ++j) v[j] = f2bf(s[j]);
    *(ulonglong2*)(dst + (size_t)i * 8) = *(ulonglong2*)v;
  }
}

// ---------------------------------------------------------------------------
// C[M][N] = A[M][K] @ B[N][K]^T, bf16, fp32 accum. m97 structure (verified)
// + XCD-aware bijective block swizzle (T1, correctness-neutral permutation):
// same-XCD-resident blocks get consecutive tiles along x -> shared B panel
// (524 KB) stays hot in that XCD's private L2 instead of being re-fetched
// by all 8 XCDs. Requires gridDim.x*gridDim.y % 8 == 0 (768/512: ok).
// NOTE (session log): R2/R3's 256^2 counted-vmcnt rewrite raced on replay;
// R5's RoPE-fused epilogue failed 0.173 with no locatable bug. Both reverted.
// Only permutation-level changes on this kernel until a faithful m201 port.
// ---------------------------------------------------------------------------
__global__ __launch_bounds__(256) void gemm_bt(const u16* __restrict__ A,
                                               const u16* __restrict__ B,
                                               u16* __restrict__ C,
                                               int M, int N, int K) {
  __shared__ __align__(16) u16 As[128 * 32];
  __shared__ __align__(16) u16 Bs[128 * 32];
  const int nbx = gridDim.x, nwg = nbx * gridDim.y;
  int fid = blockIdx.y * nbx + blockIdx.x;
  fid = (fid & 7) * (nwg >> 3) + (fid >> 3);  // bijective XCD swizzle
  const int m0 = (fid % nbx) * 128, n0 = (fid / nbx) * 128;
  const int t = threadIdx.x, wave = t >> 6, lane = t & 63;
  const int l15 = lane & 15, quad = lane >> 4;
  const int wm = (wave >> 1) * 64, wn = (wave & 1) * 64;

  f32x4 acc[4][4];
#pragma unroll
  for (int i = 0; i < 4; ++i)
#pragma unroll
    for (int j = 0; j < 4; ++j) acc[i][j] = (f32x4)(0.0f);

  for (int k0 = 0; k0 < K; k0 += 32) {
    __syncthreads();
#pragma unroll
    for (int p = 0; p < 2; ++p) {
      int slot = p * 256 + t;
      int r = slot >> 2, kk = (slot & 3) << 3;
      GLOAD_LDS(A + (size_t)(m0 + r) * K + k0 + kk, As + slot * 8);
      GLOAD_LDS(B + (size_t)(n0 + r) * K + k0 + kk, Bs + slot * 8);
    }
    __syncthreads();
    bf16x8 af[4], bfr[4];
#pragma unroll
    for (int i = 0; i < 4; ++i)
      af[i] = *(const bf16x8*)&As[(wm + i * 16 + l15) * 32 + quad * 8];
#pragma unroll
    for (int j = 0; j < 4; ++j)
      bfr[j] = *(const bf16x8*)&Bs[(wn + j * 16 + l15) * 32 + quad * 8];
#pragma unroll
    for (int i = 0; i < 4; ++i)
#pragma unroll
      for (int j = 0; j < 4; ++j) acc[i][j] = MFMA16(af[i], bfr[j], acc[i][j]);
  }
#pragma unroll
  for (int i = 0; i < 4; ++i)
#pragma unroll
    for (int j = 0; j < 4; ++j)
#pragma unroll
      for (int r = 0; r < 4; ++r) {
        int row = m0 + wm + i * 16 + quad * 4 + r;
        int col = n0 + wn + j * 16 + l15;
        C[(size_t)row * N + col] = f2bf(acc[i][j][r]);
      }
}

// Final projection GEMM with dtype-flagged store to d_out. Same swizzle.
__global__ __launch_bounds__(256) void gemm_bt_out(const u16* __restrict__ A,
                                                   const u16* __restrict__ B,
                                                   void* __restrict__ C,
                                                   int M, int N, int K,
                                                   const int* __restrict__ flag) {
  __shared__ __align__(16) u16 As[128 * 32];
  __shared__ __align__(16) u16 Bs[128 * 32];
  const int nbx = gridDim.x, nwg = nbx * gridDim.y;
  int fid = blockIdx.y * nbx + blockIdx.x;
  fid = (fid & 7) * (nwg >> 3) + (fid >> 3);  // bijective XCD swizzle
  const int m0 = (fid % nbx) * 128, n0 = (fid / nbx) * 128;
  const int t = threadIdx.x, wave = t >> 6, lane = t & 63;
  const int l15 = lane & 15, quad = lane >> 4;
  const int wm = (wave >> 1) * 64, wn = (wave & 1) * 64;
  const int f = *flag;

  f32x4 acc[4][4];
#pragma unroll
  for (int i = 0; i < 4; ++i)
#pragma unroll
    for (int j = 0; j < 4; ++j) acc[i][j] = (f32x4)(0.0f);

  for (int k0 = 0; k0 < K; k0 += 32) {
    __syncthreads();
#pragma unroll
    for (int p = 0; p < 2; ++p) {
      int slot = p * 256 + t;
      int r = slot >> 2, kk = (slot & 3) << 3;
      GLOAD_LDS(A + (size_t)(m0 + r) * K + k0 + kk, As + slot * 8);
      GLOAD_LDS(B + (size_t)(n0 + r) * K + k0 + kk, Bs + slot * 8);
    }
    __syncthreads();
    bf16x8 af[4], bfr[4];
#pragma unroll
    for (int i = 0; i < 4; ++i)
      af[i] = *(const bf16x8*)&As[(wm + i * 16 + l15) * 32 + quad * 8];
#pragma unroll
    for (int j = 0; j < 4; ++j)
      bfr[j] = *(const bf16x8*)&Bs[(wn + j * 16 + l15) * 32 + quad * 8];
#pragma unroll
    for (int i = 0; i < 4; ++i)
#pragma unroll
      for (int j = 0; j < 4; ++j) acc[i][j] = MFMA16(af[i], bfr[j], acc[i][j]);
  }
#pragma unroll
  for (int i = 0; i < 4; ++i)
#pragma unroll
    for (int j = 0; j < 4; ++j)
#pragma unroll
      for (int r = 0; r < 4; ++r) {
        int row = m0 + wm + i * 16 + quad * 4 + r;
        int col = n0 + wn + j * 16 + l15;
        size_t idx = (size_t)row * N + col;
        if (f) ((u16*)C)[idx] = f2bf(acc[i][j][r]);
        else   ((float*)C)[idx] = acc[i][j][r];
      }
}

// ---------------------------------------------------------------------------
// Transpose external weight (fp32/bf16 per flag) -> internal bf16.
// ---------------------------------------------------------------------------
__global__ __launch_bounds__(256) void transpose_any(const void* __restrict__ src,
                                                     u16* __restrict__ dst,
                                                     int src_ld, int dst_ld,
                                                     const int* __restrict__ flag) {
  __shared__ u16 tile[64][65];
  int c0 = blockIdx.x * 64, r0 = blockIdx.y * 64;
  const int f = *flag;
  for (int p = threadIdx.x; p < 4096; p += 256) {
    int r = p >> 6, c = p & 63;
    size_t idx = (size_t)(r0 + r) * src_ld + c0 + c;
    tile[r][c] = f ? ((const u16*)src)[idx] : f2bf(((const float*)src)[idx]);
  }
  __syncthreads();
  for (int p = threadIdx.x; p < 4096; p += 256) {
    int c = p >> 6, r = p & 63;
    dst[(size_t)(c0 + c) * dst_ld + r0 + r] = tile[r][c];
  }
}

__global__ __launch_bounds__(256) void v_transpose(const u16* __restrict__ Cqkv,
                                                   u16* __restrict__ Vt) {
  __shared__ u16 tile[64][65];
  int s0 = blockIdx.x * 64, d0 = blockIdx.y * 64, z = blockIdx.z;
  int b = z >> 2, kvh = z & 3;
  const u16* src = Cqkv + (size_t)b * 2048 * 3072 + 2560 + kvh * 128;
  u16* dst = Vt + (size_t)z * 128 * 2048;
  for (int p = threadIdx.x; p < 4096; p += 256) {
    int r = p >> 6, c = p & 63;
    tile[r][c] = src[(size_t)(s0 + r) * 3072 + d0 + c];
  }
  __syncthreads();
  for (int p = threadIdx.x; p < 4096; p += 256) {
    int c = p >> 6, r = p & 63;
    dst[(size_t)(d0 + c) * 2048 + s0 + r] = tile[r][c];
  }
}

// ---------------------------------------------------------------------------
// In-place RoPE. Q scaled by HD^-0.5 * log2(e): attention runs in exp2 domain.
// [verified] NOTE: R5 tried fusing this into the QKV GEMM epilogue via
// __shfl_xor pair exchange; failed absmax 0.173 with no locatable bug after
// 3 audits. Keep as separate pass.
// ---------------------------------------------------------------------------
__global__ __launch_bounds__(256) void rope_inplace(u16* __restrict__ Cqkv,
                                                    const u16* __restrict__ cosT,
                                                    const u16* __restrict__ sinT) {
  const float SCALE = 0.12751742f;  // 128^-0.5 * log2(e)
  int rid = blockIdx.x;
  int s = rid & 2047;
  u16* row = Cqkv + (size_t)rid * 3072;
  for (int p = threadIdx.x; p < 1280; p += 256) {
    int col, i;
    float scale;
    if (p < 1024) {
      col = (p >> 6) * 128 + 2 * (p & 63);
      i = p & 63;
      scale = SCALE;
    } else {
      int pp = p - 1024;
      col = 2048 + (pp >> 6) * 128 + 2 * (pp & 63);
      i = pp & 63;
      scale = 1.0f;
    }
    unsigned pr = *(const unsigned*)(row + col);
    float x1 = bf2f((u16)(pr & 0xFFFF)), x2 = bf2f((u16)(pr >> 16));
    float c = bf2f(cosT[s * 64 + i]), sn = bf2f(sinT[s * 64 + i]);
    float o1 = (x1 * c - x2 * sn) * scale;
    float o2 = (x1 * sn + x2 * c) * scale;
    *(unsigned*)(row + col) = (unsigned)f2bf(o1) | ((unsigned)f2bf(o2) << 16);
  }
}

// ---------------------------------------------------------------------------
// Flash attention v6: one q-tile per block, 4 blocks/CU + T5 setprio
// (verified R4).
// ---------------------------------------------------------------------------
__global__ __launch_bounds__(256, 4) void attn(const u16* __restrict__ Cqkv,
                                               const u16* __restrict__ Vt,
                                               u16* __restrict__ O) {
  __shared__ __align__(16) u16 lds[2 * 4096 + 2 * 4096 + 4 * 640];
  const float NEGI = -1e30f;
  const int pair = blockIdx.x, h = blockIdx.y, z = blockIdx.z;
  const int b = z >> 1, ph = z & 1;
  const int kvh = h >> 2;
  const int t = threadIdx.x, wave = t >> 6, lane = t & 63;
  const int l15 = lane & 15, quad = lane >> 4;
  const int krow0 = b * 2048;
  const size_t vbase = ((size_t)b * 4 + kvh) * 128 * 2048;
  const u16* Kg = Cqkv + 2048 + kvh * 128;
  const u16* Qg = Cqkv + h * 128;
  u16* KsB = lds;                       // [2][32*128]
  u16* VsB = lds + 8192;                // [2][128*32]
  u16* PsW = lds + 16384 + wave * 640;  // 16 rows x stride 40
  u16* OsW = lds + wave * 2176;         // epilogue only: 16 rows x stride 136

  const int qt = ph ? (31 - pair) : pair;       // 64-row q tile, 0..31
  const int qrow0 = b * 2048 + qt * 64;         // global row base
  const int q0w = qt * 64 + wave * 16;          // wave's q range start (seq)
  const int myq = q0w + l15;                    // this lane's q (seq)

  // Q fragments -> registers (one row per lane, 4 chunks of 16B)
  bf16x8 qreg[4];
#pragma unroll
  for (int ks = 0; ks < 4; ++ks)
    qreg[ks] = *(const bf16x8*)(Qg + (size_t)(qrow0 + wave * 16 + l15) * 3072 +
                                ks * 32 + quad * 8);
  // prefetch kv tile 0 into buf 0
#pragma unroll
  for (int p = 0; p < 2; ++p) {
    int slot = p * 256 + t;
    int r = slot >> 4;
    int ch = (slot & 15) ^ (r & 15);
    GLOAD_LDS(Kg + (size_t)(krow0 + r) * 3072 + ch * 8, KsB + slot * 8);
  }
#pragma unroll
  for (int p = 0; p < 2; ++p) {
    int slot = p * 256 + t;
    int vr = slot >> 2;
    int vc = ((slot & 3) ^ ((vr >> 1) & 3)) << 3;
    GLOAD_LDS(Vt + vbase + (size_t)vr * 2048 + vc, VsB + slot * 8);
  }

  float l_lane = 0.f;  // this lane's partial sum over its 8 kv per tile
  f32x4 oacc[8];
#pragma unroll
  for (int jd = 0; jd < 8; ++jd) oacc[jd] = (f32x4)(0.0f);

  const int nt = 2 * (qt + 1);
  for (int it = 0; it < nt; ++it) {
    const int k0 = it * 32;
    __syncthreads();  // drains prefetch of tile it; signals buf (it+1)&1 free
    if (it + 1 < nt) {
      const int kn = k0 + 32;
      u16* kb = KsB + ((it + 1) & 1) * 4096;
      u16* vb = VsB + ((it + 1) & 1) * 4096;
#pragma unroll
      for (int p = 0; p < 2; ++p) {
        int slot = p * 256 + t;
        int r = slot >> 4;
        int ch = (slot & 15) ^ (r & 15);
        GLOAD_LDS(Kg + (size_t)(krow0 + kn + r) * 3072 + ch * 8, kb + slot * 8);
      }
#pragma unroll
      for (int p = 0; p < 2; ++p) {
        int slot = p * 256 + t;
        int vr = slot >> 2;
        int vc = ((slot & 3) ^ ((vr >> 1) & 3)) << 3;
        GLOAD_LDS(Vt + vbase + (size_t)vr * 2048 + kn + vc, vb + slot * 8);
      }
    }
    if (k0 > q0w + 15) continue;  // tile fully masked for this wave

    const u16* kb = KsB + (it & 1) * 4096;
    const u16* vb = VsB + (it & 1) * 4096;
    // S^T = K @ Q^T : rows kv (2x16), cols q (16)
    f32x4 sc[2];
    sc[0] = (f32x4)(0.f); sc[1] = (f32x4)(0.f);
    __builtin_amdgcn_s_setprio(1);
#pragma unroll
    for (int ks = 0; ks < 4; ++ks) {
      int chs = ((ks * 4 + quad) ^ l15) * 8;
      bf16x8 kf0 = *(const bf16x8*)&kb[l15 * 128 + chs];
      bf16x8 kf1 = *(const bf16x8*)&kb[(16 + l15) * 128 + chs];
      sc[0] = MFMA16(kf0, qreg[ks], sc[0]);
      sc[1] = MFMA16(kf1, qreg[ks], sc[1]);
    }
    __builtin_amdgcn_s_setprio(0);
    // causal mask — only diagonal tiles need it (wave-uniform branch)
    if (k0 + 31 > q0w) {
#pragma unroll
      for (int j = 0; j < 2; ++j)
#pragma unroll
        for (int r = 0; r < 4; ++r) {
          int kv = k0 + j * 16 + quad * 4 + r;
          if (kv > myq) sc[j][r] = NEGI;
        }
    }
    // direct exp2 softmax: P = exp2(s); l accumulated from truncated P so
    // normalization matches stored bf16 P exactly.
    u16 pb[8];
#pragma unroll
    for (int j = 0; j < 2; ++j)
#pragma unroll
      for (int r = 0; r < 4; ++r) {
        float pv = __builtin_amdgcn_exp2f(sc[j][r]);
        unsigned bits = __float_as_uint(pv);
        l_lane += __uint_as_float(bits & 0xFFFF0000u);
        pb[j * 4 + r] = (u16)(bits >> 16);
      }
    // P -> Ps[q][kv] (stride 40), 2 x ds_write_b64, then B-frag read (in-wave)
#pragma unroll
    for (int j = 0; j < 2; ++j) {
      u64 pk = (u64)pb[j * 4] | ((u64)pb[j * 4 + 1] << 16) |
               ((u64)pb[j * 4 + 2] << 32) | ((u64)pb[j * 4 + 3] << 48);
      *(u64*)&PsW[l15 * 40 + j * 16 + quad * 4] = pk;
    }
    bf16x8 pf = *(const bf16x8*)&PsW[l15 * 40 + quad * 8];
    // O^T += V^T @ P
    __builtin_amdgcn_s_setprio(1);
#pragma unroll
    for (int jd = 0; jd < 8; ++jd) {
      int d = jd * 16 + l15;
      bf16x8 vf = *(const bf16x8*)&vb[d * 32 + ((quad ^ ((l15 >> 1) & 3)) << 3)];
      oacc[jd] = MFMA16(vf, pf, oacc[jd]);
    }
    __builtin_amdgcn_s_setprio(0);
  }
  __syncthreads();  // all waves done with K/V LDS before Os overlays it

  // final l for this q row: reduce partial sums across the 4 quads
  float l_st = l_lane;
  l_st += __shfl_xor(l_st, 16);
  l_st += __shfl_xor(l_st, 32);
  float inv = 1.0f / l_st;

  // epilogue: O^T -> LDS transpose -> coalesced global O[b*S+q][h*128+d]
#pragma unroll
  for (int jd = 0; jd < 8; ++jd) {
    u64 pk = (u64)f2bf(oacc[jd][0] * inv) | ((u64)f2bf(oacc[jd][1] * inv) << 16) |
             ((u64)f2bf(oacc[jd][2] * inv) << 32) | ((u64)f2bf(oacc[jd][3] * inv) << 48);
    *(u64*)&OsW[l15 * 136 + jd * 16 + quad * 4] = pk;
  }
#pragma unroll
  for (int rr = 0; rr < 4; ++rr) {
    int row = rr * 4 + quad;
    bf16x8 ov = *(const bf16x8*)&OsW[row * 136 + l15 * 8];
    *(bf16x8*)&O[(size_t)(qrow0 + wave * 16 + row) * 2048 + h * 128 + l15 * 8] = ov;
  }
}

// ---------------------------------------------------------------------------
// Workspace plan (55.1 MB peak) — unchanged (verified passing).
// ---------------------------------------------------------------------------
extern "C" void kernel_launch(void* const* d_in, const int* in_sizes, int n_in,
                              void* d_out, int out_size, void* d_ws, size_t ws_size,
                              hipStream_t stream) {
  const void* x    = d_in[0];
  const void* cosI = d_in[2];
  const void* sinI = d_in[3];
  const void* Wq   = d_in[4];
  const void* Wkv  = d_in[5];
  const void* Wo   = d_in[6];

  char* ws = (char*)d_ws;
  u16* Cqkv  = (u16*)ws;
  u16* xb    = (u16*)(ws + 25165824);
  u16* Vt    = (u16*)(ws + 25165824);
  u16* Oreg  = (u16*)(ws + 29360128);
  u16* WqkvT = (u16*)(ws + 41943040);
  u16* cosb  = (u16*)(ws + 54525952);
  u16* sinb  = (u16*)(ws + 54788096);
  int* flag  = (int*)(ws + 55050240);
  u16* WoT   = Cqkv;

  detect_dtype<<<1, 256, 0, stream>>>((const unsigned*)x, flag);
  cvt_bf16<<<4096, 256, 0, stream>>>(x, xb, 1048576, flag);
  cvt_bf16_2<<<128, 256, 0, stream>>>(cosI, sinI, cosb, sinb, 16384, flag);
  transpose_any<<<dim3(32, 32), 256, 0, stream>>>(Wq, WqkvT, 2048, 2048, flag);
  transpose_any<<<dim3(16, 32), 256, 0, stream>>>(Wkv, WqkvT + (size_t)2048 * 2048,
                                                  1024, 2048, flag);
  gemm_bt<<<dim3(32, 24), 256, 0, stream>>>(xb, WqkvT, Cqkv, 4096, 3072, 2048);
  rope_inplace<<<4096, 256, 0, stream>>>(Cqkv, cosb, sinb);
  v_transpose<<<dim3(32, 2, 8), 256, 0, stream>>>(Cqkv, Vt);
  attn<<<dim3(16, 16, 4), 256, 0, stream>>>(Cqkv, Vt, Oreg);
  transpose_any<<<dim3(32, 32), 256, 0, stream>>>(Wo, WoT, 2048, 2048, flag);
  gemm_bt_out<<<dim3(32, 16), 256, 0, stream>>>(Oreg, WoT, d_out, 4096, 2048, 2048, flag);
}

// Round 7
// 360.588 us; speedup vs baseline: 1.0074x; 1.0074x over previous
//
#include <hip/hip_runtime.h>

typedef unsigned short u16;
typedef unsigned long long u64;
typedef __attribute__((ext_vector_type(8))) short bf16x8;
typedef __attribute__((ext_vector_type(4))) float f32x4;

// async global->LDS, 16B per lane. LDS dest must be wave-uniform base + lane*16.
#define GLOAD_LDS(gptr, lptr)                                                            \
  __builtin_amdgcn_global_load_lds(                                                      \
      (const __attribute__((address_space(1))) unsigned int*)(gptr),                     \
      (__attribute__((address_space(3))) unsigned int*)(lptr), 16, 0, 0)

__device__ __forceinline__ float bf2f(u16 u) {
  union { unsigned v; float f; } x; x.v = ((unsigned)u) << 16; return x.f;
}
__device__ __forceinline__ u16 f2bf(float f) {
  union { float f; unsigned v; } x; x.f = f;
  unsigned r = x.v + 0x7FFFu + ((x.v >> 16) & 1u);
  return (u16)(r >> 16);
}

#define MFMA16(a, b, c) __builtin_amdgcn_mfma_f32_16x16x32_bf16((a), (b), (c), 0, 0, 0)

// ---------------------------------------------------------------------------
// Dtype probe (R5-verified: inputs are fp32; probe kept for robustness).
// ---------------------------------------------------------------------------
__global__ __launch_bounds__(256) void detect_dtype(const unsigned* __restrict__ x,
                                                    int* __restrict__ flag) {
  __shared__ int cnt;
  if (threadIdx.x == 0) cnt = 0;
  __syncthreads();
  int local = 0;
  for (int i = threadIdx.x; i < 2048; i += 256) {
    unsigned w = x[i];
    int e = (w >> 7) & 0xFF;
    if (e >= 118 && e <= 130) local++;
  }
  atomicAdd(&cnt, local);
  __syncthreads();
  if (threadIdx.x == 0) *flag = (cnt > 1024) ? 1 : 0;
}

__global__ __launch_bounds__(256) void cvt_bf16(const void* __restrict__ src,
                                                u16* __restrict__ dst, int n8,
                                                const int* __restrict__ flag) {
  int i = blockIdx.x * 256 + threadIdx.x;
  if (i >= n8) return;
  if (*flag) {
    ((ulonglong2*)dst)[i] = ((const ulonglong2*)src)[i];
  } else {
    const float* s = (const float*)src + (size_t)i * 8;
    u16 v[8];
#pragma unroll
    for (int j = 0; j < 8; ++j) v[j] = f2bf(s[j]);
    *(ulonglong2*)(dst + (size_t)i * 8) = *(ulonglong2*)v;
  }
}

// cos+sin tables converted in one launch (two tiny launches fused). [R4-verified]
__global__ __launch_bounds__(256) void cvt_bf16_2(const void* __restrict__ src0,
                                                  const void* __restrict__ src1,
                                                  u16* __restrict__ dst0,
                                                  u16* __restrict__ dst1, int n8,
                                                  const int* __restrict__ flag) {
  int half = gridDim.x >> 1;
  const void* src = (blockIdx.x < half) ? src0 : src1;
  u16* dst = (blockIdx.x < half) ? dst0 : dst1;
  int i = (blockIdx.x < half ? blockIdx.x : blockIdx.x - half) * 256 + threadIdx.x;
  if (i >= n8) return;
  if (*flag) {
    ((ulonglong2*)dst)[i] = ((const ulonglong2*)src)[i];
  } else {
    const float* s = (const float*)src + (size_t)i * 8;
    u16 v[8];
#pragma unroll
    for (int j = 0; j < 8; ++j) v[j] = f2bf(s[j]);
    *(ulonglong2*)(dst + (size_t)i * 8) = *(ulonglong2*)v;
  }
}

// ---------------------------------------------------------------------------
// C[M][N] = A[M][K] @ B[N][K]^T, bf16, fp32 accum. m97 structure (verified)
// + both-sides XOR bank-conflict fix (rule #21, same pattern as attn staging):
//   [128][32] tile (64B row stride) put each ds_read_b128 frag load at
//   bank-slot (row&1, quad) -> 8-way conflict (6.29M conflict cycles/dispatch
//   = ~14% of CU time). Fix: pre-swizzle GLOBAL source chunk with ((r>>1)&3)
//   (LDS dest stays linear per global_load_lds) and read physical chunk
//   quad ^ ((row>>1)&3). Bank-slot becomes (row&1, quad^((row>>1)&3)) ->
//   exactly 2 rows/slot -> 2-way = free (m136). Math/data unchanged.
// SESSION LOG: R2/R3 256^2 counted-vmcnt rewrite raced on replay; R5
// RoPE-fused epilogue failed (0.173); R6 XCD swizzle regressed (inputs are
// L3-resident; m160: swizzle costs when L3-fit). All reverted.
// ---------------------------------------------------------------------------
__global__ __launch_bounds__(256) void gemm_bt(const u16* __restrict__ A,
                                               const u16* __restrict__ B,
                                               u16* __restrict__ C,
                                               int M, int N, int K) {
  __shared__ __align__(16) u16 As[128 * 32];
  __shared__ __align__(16) u16 Bs[128 * 32];
  const int m0 = blockIdx.x * 128, n0 = blockIdx.y * 128;
  const int t = threadIdx.x, wave = t >> 6, lane = t & 63;
  const int l15 = lane & 15, quad = lane >> 4;
  const int wm = (wave >> 1) * 64, wn = (wave & 1) * 64;

  f32x4 acc[4][4];
#pragma unroll
  for (int i = 0; i < 4; ++i)
#pragma unroll
    for (int j = 0; j < 4; ++j) acc[i][j] = (f32x4)(0.0f);

  for (int k0 = 0; k0 < K; k0 += 32) {
    __syncthreads();
#pragma unroll
    for (int p = 0; p < 2; ++p) {
      int slot = p * 256 + t;
      int r = slot >> 2;
      int kk = ((slot & 3) ^ ((r >> 1) & 3)) << 3;  // inverse-swizzled source
      GLOAD_LDS(A + (size_t)(m0 + r) * K + k0 + kk, As + slot * 8);
      GLOAD_LDS(B + (size_t)(n0 + r) * K + k0 + kk, Bs + slot * 8);
    }
    __syncthreads();
    bf16x8 af[4], bfr[4];
#pragma unroll
    for (int i = 0; i < 4; ++i) {
      int row = wm + i * 16 + l15;
      af[i] = *(const bf16x8*)&As[row * 32 + ((quad ^ ((row >> 1) & 3)) << 3)];
    }
#pragma unroll
    for (int j = 0; j < 4; ++j) {
      int row = wn + j * 16 + l15;
      bfr[j] = *(const bf16x8*)&Bs[row * 32 + ((quad ^ ((row >> 1) & 3)) << 3)];
    }
#pragma unroll
    for (int i = 0; i < 4; ++i)
#pragma unroll
      for (int j = 0; j < 4; ++j) acc[i][j] = MFMA16(af[i], bfr[j], acc[i][j]);
  }
#pragma unroll
  for (int i = 0; i < 4; ++i)
#pragma unroll
    for (int j = 0; j < 4; ++j)
#pragma unroll
      for (int r = 0; r < 4; ++r) {
        int row = m0 + wm + i * 16 + quad * 4 + r;
        int col = n0 + wn + j * 16 + l15;
        C[(size_t)row * N + col] = f2bf(acc[i][j][r]);
      }
}

// Final projection GEMM with dtype-flagged store to d_out. Same bank fix.
__global__ __launch_bounds__(256) void gemm_bt_out(const u16* __restrict__ A,
                                                   const u16* __restrict__ B,
                                                   void* __restrict__ C,
                                                   int M, int N, int K,
                                                   const int* __restrict__ flag) {
  __shared__ __align__(16) u16 As[128 * 32];
  __shared__ __align__(16) u16 Bs[128 * 32];
  const int m0 = blockIdx.x * 128, n0 = blockIdx.y * 128;
  const int t = threadIdx.x, wave = t >> 6, lane = t & 63;
  const int l15 = lane & 15, quad = lane >> 4;
  const int wm = (wave >> 1) * 64, wn = (wave & 1) * 64;
  const int f = *flag;

  f32x4 acc[4][4];
#pragma unroll
  for (int i = 0; i < 4; ++i)
#pragma unroll
    for (int j = 0; j < 4; ++j) acc[i][j] = (f32x4)(0.0f);

  for (int k0 = 0; k0 < K; k0 += 32) {
    __syncthreads();
#pragma unroll
    for (int p = 0; p < 2; ++p) {
      int slot = p * 256 + t;
      int r = slot >> 2;
      int kk = ((slot & 3) ^ ((r >> 1) & 3)) << 3;  // inverse-swizzled source
      GLOAD_LDS(A + (size_t)(m0 + r) * K + k0 + kk, As + slot * 8);
      GLOAD_LDS(B + (size_t)(n0 + r) * K + k0 + kk, Bs + slot * 8);
    }
    __syncthreads();
    bf16x8 af[4], bfr[4];
#pragma unroll
    for (int i = 0; i < 4; ++i) {
      int row = wm + i * 16 + l15;
      af[i] = *(const bf16x8*)&As[row * 32 + ((quad ^ ((row >> 1) & 3)) << 3)];
    }
#pragma unroll
    for (int j = 0; j < 4; ++j) {
      int row = wn + j * 16 + l15;
      bfr[j] = *(const bf16x8*)&Bs[row * 32 + ((quad ^ ((row >> 1) & 3)) << 3)];
    }
#pragma unroll
    for (int i = 0; i < 4; ++i)
#pragma unroll
      for (int j = 0; j < 4; ++j) acc[i][j] = MFMA16(af[i], bfr[j], acc[i][j]);
  }
#pragma unroll
  for (int i = 0; i < 4; ++i)
#pragma unroll
    for (int j = 0; j < 4; ++j)
#pragma unroll
      for (int r = 0; r < 4; ++r) {
        int row = m0 + wm + i * 16 + quad * 4 + r;
        int col = n0 + wn + j * 16 + l15;
        size_t idx = (size_t)row * N + col;
        if (f) ((u16*)C)[idx] = f2bf(acc[i][j][r]);
        else   ((float*)C)[idx] = acc[i][j][r];
      }
}

// ---------------------------------------------------------------------------
// Transpose external weight (fp32/bf16 per flag) -> internal bf16.
// ---------------------------------------------------------------------------
__global__ __launch_bounds__(256) void transpose_any(const void* __restrict__ src,
                                                     u16* __restrict__ dst,
                                                     int src_ld, int dst_ld,
                                                     const int* __restrict__ flag) {
  __shared__ u16 tile[64][65];
  int c0 = blockIdx.x * 64, r0 = blockIdx.y * 64;
  const int f = *flag;
  for (int p = threadIdx.x; p < 4096; p += 256) {
    int r = p >> 6, c = p & 63;
    size_t idx = (size_t)(r0 + r) * src_ld + c0 + c;
    tile[r][c] = f ? ((const u16*)src)[idx] : f2bf(((const float*)src)[idx]);
  }
  __syncthreads();
  for (int p = threadIdx.x; p < 4096; p += 256) {
    int c = p >> 6, r = p & 63;
    dst[(size_t)(c0 + c) * dst_ld + r0 + r] = tile[r][c];
  }
}

__global__ __launch_bounds__(256) void v_transpose(const u16* __restrict__ Cqkv,
                                                   u16* __restrict__ Vt) {
  __shared__ u16 tile[64][65];
  int s0 = blockIdx.x * 64, d0 = blockIdx.y * 64, z = blockIdx.z;
  int b = z >> 2, kvh = z & 3;
  const u16* src = Cqkv + (size_t)b * 2048 * 3072 + 2560 + kvh * 128;
  u16* dst = Vt + (size_t)z * 128 * 2048;
  for (int p = threadIdx.x; p < 4096; p += 256) {
    int r = p >> 6, c = p & 63;
    tile[r][c] = src[(size_t)(s0 + r) * 3072 + d0 + c];
  }
  __syncthreads();
  for (int p = threadIdx.x; p < 4096; p += 256) {
    int c = p >> 6, r = p & 63;
    dst[(size_t)(d0 + c) * 2048 + s0 + r] = tile[r][c];
  }
}

// ---------------------------------------------------------------------------
// In-place RoPE. Q scaled by HD^-0.5 * log2(e): attention runs in exp2 domain.
// [verified] R5's GEMM-epilogue fusion failed (0.173, unlocatable); keep
// as separate pass.
// ---------------------------------------------------------------------------
__global__ __launch_bounds__(256) void rope_inplace(u16* __restrict__ Cqkv,
                                                    const u16* __restrict__ cosT,
                                                    const u16* __restrict__ sinT) {
  const float SCALE = 0.12751742f;  // 128^-0.5 * log2(e)
  int rid = blockIdx.x;
  int s = rid & 2047;
  u16* row = Cqkv + (size_t)rid * 3072;
  for (int p = threadIdx.x; p < 1280; p += 256) {
    int col, i;
    float scale;
    if (p < 1024) {
      col = (p >> 6) * 128 + 2 * (p & 63);
      i = p & 63;
      scale = SCALE;
    } else {
      int pp = p - 1024;
      col = 2048 + (pp >> 6) * 128 + 2 * (pp & 63);
      i = pp & 63;
      scale = 1.0f;
    }
    unsigned pr = *(const unsigned*)(row + col);
    float x1 = bf2f((u16)(pr & 0xFFFF)), x2 = bf2f((u16)(pr >> 16));
    float c = bf2f(cosT[s * 64 + i]), sn = bf2f(sinT[s * 64 + i]);
    float o1 = (x1 * c - x2 * sn) * scale;
    float o2 = (x1 * sn + x2 * c) * scale;
    *(unsigned*)(row + col) = (unsigned)f2bf(o1) | ((unsigned)f2bf(o2) << 16);
  }
}

// ---------------------------------------------------------------------------
// Flash attention v6: one q-tile per block, 4 blocks/CU + T5 setprio
// (verified R4).
// ---------------------------------------------------------------------------
__global__ __launch_bounds__(256, 4) void attn(const u16* __restrict__ Cqkv,
                                               const u16* __restrict__ Vt,
                                               u16* __restrict__ O) {
  __shared__ __align__(16) u16 lds[2 * 4096 + 2 * 4096 + 4 * 640];
  const float NEGI = -1e30f;
  const int pair = blockIdx.x, h = blockIdx.y, z = blockIdx.z;
  const int b = z >> 1, ph = z & 1;
  const int kvh = h >> 2;
  const int t = threadIdx.x, wave = t >> 6, lane = t & 63;
  const int l15 = lane & 15, quad = lane >> 4;
  const int krow0 = b * 2048;
  const size_t vbase = ((size_t)b * 4 + kvh) * 128 * 2048;
  const u16* Kg = Cqkv + 2048 + kvh * 128;
  const u16* Qg = Cqkv + h * 128;
  u16* KsB = lds;                       // [2][32*128]
  u16* VsB = lds + 8192;                // [2][128*32]
  u16* PsW = lds + 16384 + wave * 640;  // 16 rows x stride 40
  u16* OsW = lds + wave * 2176;         // epilogue only: 16 rows x stride 136

  const int qt = ph ? (31 - pair) : pair;       // 64-row q tile, 0..31
  const int qrow0 = b * 2048 + qt * 64;         // global row base
  const int q0w = qt * 64 + wave * 16;          // wave's q range start (seq)
  const int myq = q0w + l15;                    // this lane's q (seq)

  // Q fragments -> registers (one row per lane, 4 chunks of 16B)
  bf16x8 qreg[4];
#pragma unroll
  for (int ks = 0; ks < 4; ++ks)
    qreg[ks] = *(const bf16x8*)(Qg + (size_t)(qrow0 + wave * 16 + l15) * 3072 +
                                ks * 32 + quad * 8);
  // prefetch kv tile 0 into buf 0
#pragma unroll
  for (int p = 0; p < 2; ++p) {
    int slot = p * 256 + t;
    int r = slot >> 4;
    int ch = (slot & 15) ^ (r & 15);
    GLOAD_LDS(Kg + (size_t)(krow0 + r) * 3072 + ch * 8, KsB + slot * 8);
  }
#pragma unroll
  for (int p = 0; p < 2; ++p) {
    int slot = p * 256 + t;
    int vr = slot >> 2;
    int vc = ((slot & 3) ^ ((vr >> 1) & 3)) << 3;
    GLOAD_LDS(Vt + vbase + (size_t)vr * 2048 + vc, VsB + slot * 8);
  }

  float l_lane = 0.f;  // this lane's partial sum over its 8 kv per tile
  f32x4 oacc[8];
#pragma unroll
  for (int jd = 0; jd < 8; ++jd) oacc[jd] = (f32x4)(0.0f);

  const int nt = 2 * (qt + 1);
  for (int it = 0; it < nt; ++it) {
    const int k0 = it * 32;
    __syncthreads();  // drains prefetch of tile it; signals buf (it+1)&1 free
    if (it + 1 < nt) {
      const int kn = k0 + 32;
      u16* kb = KsB + ((it + 1) & 1) * 4096;
      u16* vb = VsB + ((it + 1) & 1) * 4096;
#pragma unroll
      for (int p = 0; p < 2; ++p) {
        int slot = p * 256 + t;
        int r = slot >> 4;
        int ch = (slot & 15) ^ (r & 15);
        GLOAD_LDS(Kg + (size_t)(krow0 + kn + r) * 3072 + ch * 8, kb + slot * 8);
      }
#pragma unroll
      for (int p = 0; p < 2; ++p) {
        int slot = p * 256 + t;
        int vr = slot >> 2;
        int vc = ((slot & 3) ^ ((vr >> 1) & 3)) << 3;
        GLOAD_LDS(Vt + vbase + (size_t)vr * 2048 + kn + vc, vb + slot * 8);
      }
    }
    if (k0 > q0w + 15) continue;  // tile fully masked for this wave

    const u16* kb = KsB + (it & 1) * 4096;
    const u16* vb = VsB + (it & 1) * 4096;
    // S^T = K @ Q^T : rows kv (2x16), cols q (16)
    f32x4 sc[2];
    sc[0] = (f32x4)(0.f); sc[1] = (f32x4)(0.f);
    __builtin_amdgcn_s_setprio(1);
#pragma unroll
    for (int ks = 0; ks < 4; ++ks) {
      int chs = ((ks * 4 + quad) ^ l15) * 8;
      bf16x8 kf0 = *(const bf16x8*)&kb[l15 * 128 + chs];
      bf16x8 kf1 = *(const bf16x8*)&kb[(16 + l15) * 128 + chs];
      sc[0] = MFMA16(kf0, qreg[ks], sc[0]);
      sc[1] = MFMA16(kf1, qreg[ks], sc[1]);
    }
    __builtin_amdgcn_s_setprio(0);
    // causal mask — only diagonal tiles need it (wave-uniform branch)
    if (k0 + 31 > q0w) {
#pragma unroll
      for (int j = 0; j < 2; ++j)
#pragma unroll
        for (int r = 0; r < 4; ++r) {
          int kv = k0 + j * 16 + quad * 4 + r;
          if (kv > myq) sc[j][r] = NEGI;
        }
    }
    // direct exp2 softmax: P = exp2(s); l accumulated from truncated P so
    // normalization matches stored bf16 P exactly.
    u16 pb[8];
#pragma unroll
    for (int j = 0; j < 2; ++j)
#pragma unroll
      for (int r = 0; r < 4; ++r) {
        float pv = __builtin_amdgcn_exp2f(sc[j][r]);
        unsigned bits = __float_as_uint(pv);
        l_lane += __uint_as_float(bits & 0xFFFF0000u);
        pb[j * 4 + r] = (u16)(bits >> 16);
      }
    // P -> Ps[q][kv] (stride 40), 2 x ds_write_b64, then B-frag read (in-wave)
#pragma unroll
    for (int j = 0; j < 2; ++j) {
      u64 pk = (u64)pb[j * 4] | ((u64)pb[j * 4 + 1] << 16) |
               ((u64)pb[j * 4 + 2] << 32) | ((u64)pb[j * 4 + 3] << 48);
      *(u64*)&PsW[l15 * 40 + j * 16 + quad * 4] = pk;
    }
    bf16x8 pf = *(const bf16x8*)&PsW[l15 * 40 + quad * 8];
    // O^T += V^T @ P
    __builtin_amdgcn_s_setprio(1);
#pragma unroll
    for (int jd = 0; jd < 8; ++jd) {
      int d = jd * 16 + l15;
      bf16x8 vf = *(const bf16x8*)&vb[d * 32 + ((quad ^ ((l15 >> 1) & 3)) << 3)];
      oacc[jd] = MFMA16(vf, pf, oacc[jd]);
    }
    __builtin_amdgcn_s_setprio(0);
  }
  __syncthreads();  // all waves done with K/V LDS before Os overlays it

  // final l for this q row: reduce partial sums across the 4 quads
  float l_st = l_lane;
  l_st += __shfl_xor(l_st, 16);
  l_st += __shfl_xor(l_st, 32);
  float inv = 1.0f / l_st;

  // epilogue: O^T -> LDS transpose -> coalesced global O[b*S+q][h*128+d]
#pragma unroll
  for (int jd = 0; jd < 8; ++jd) {
    u64 pk = (u64)f2bf(oacc[jd][0] * inv) | ((u64)f2bf(oacc[jd][1] * inv) << 16) |
             ((u64)f2bf(oacc[jd][2] * inv) << 32) | ((u64)f2bf(oacc[jd][3] * inv) << 48);
    *(u64*)&OsW[l15 * 136 + jd * 16 + quad * 4] = pk;
  }
#pragma unroll
  for (int rr = 0; rr < 4; ++rr) {
    int row = rr * 4 + quad;
    bf16x8 ov = *(const bf16x8*)&OsW[row * 136 + l15 * 8];
    *(bf16x8*)&O[(size_t)(qrow0 + wave * 16 + row) * 2048 + h * 128 + l15 * 8] = ov;
  }
}

// ---------------------------------------------------------------------------
// Workspace plan (55.1 MB peak) — unchanged (verified passing).
// ---------------------------------------------------------------------------
extern "C" void kernel_launch(void* const* d_in, const int* in_sizes, int n_in,
                              void* d_out, int out_size, void* d_ws, size_t ws_size,
                              hipStream_t stream) {
  const void* x    = d_in[0];
  const void* cosI = d_in[2];
  const void* sinI = d_in[3];
  const void* Wq   = d_in[4];
  const void* Wkv  = d_in[5];
  const void* Wo   = d_in[6];

  char* ws = (char*)d_ws;
  u16* Cqkv  = (u16*)ws;
  u16* xb    = (u16*)(ws + 25165824);
  u16* Vt    = (u16*)(ws + 25165824);
  u16* Oreg  = (u16*)(ws + 29360128);
  u16* WqkvT = (u16*)(ws + 41943040);
  u16* cosb  = (u16*)(ws + 54525952);
  u16* sinb  = (u16*)(ws + 54788096);
  int* flag  = (int*)(ws + 55050240);
  u16* WoT   = Cqkv;

  detect_dtype<<<1, 256, 0, stream>>>((const unsigned*)x, flag);
  cvt_bf16<<<4096, 256, 0, stream>>>(x, xb, 1048576, flag);
  cvt_bf16_2<<<128, 256, 0, stream>>>(cosI, sinI, cosb, sinb, 16384, flag);
  transpose_any<<<dim3(32, 32), 256, 0, stream>>>(Wq, WqkvT, 2048, 2048, flag);
  transpose_any<<<dim3(16, 32), 256, 0, stream>>>(Wkv, WqkvT + (size_t)2048 * 2048,
                                                  1024, 2048, flag);
  gemm_bt<<<dim3(32, 24), 256, 0, stream>>>(xb, WqkvT, Cqkv, 4096, 3072, 2048);
  rope_inplace<<<4096, 256, 0, stream>>>(Cqkv, cosb, sinb);
  v_transpose<<<dim3(32, 2, 8), 256, 0, stream>>>(Cqkv, Vt);
  attn<<<dim3(16, 16, 4), 256, 0, stream>>>(Cqkv, Vt, Oreg);
  transpose_any<<<dim3(32, 32), 256, 0, stream>>>(Wo, WoT, 2048, 2048, flag);
  gemm_bt_out<<<dim3(32, 16), 256, 0, stream>>>(Oreg, WoT, d_out, 4096, 2048, 2048, flag);
}

// Round 8
// 334.926 us; speedup vs baseline: 1.0846x; 1.0766x over previous
//
#include <hip/hip_runtime.h>

typedef unsigned short u16;
typedef unsigned long long u64;
typedef __attribute__((ext_vector_type(8))) short bf16x8;
typedef __attribute__((ext_vector_type(4))) float f32x4;

// async global->LDS, 16B per lane. LDS dest must be wave-uniform base + lane*16.
#define GLOAD_LDS(gptr, lptr)                                                            \
  __builtin_amdgcn_global_load_lds(                                                      \
      (const __attribute__((address_space(1))) unsigned int*)(gptr),                     \
      (__attribute__((address_space(3))) unsigned int*)(lptr), 16, 0, 0)

__device__ __forceinline__ float bf2f(u16 u) {
  union { unsigned v; float f; } x; x.v = ((unsigned)u) << 16; return x.f;
}
__device__ __forceinline__ u16 f2bf(float f) {
  union { float f; unsigned v; } x; x.f = f;
  unsigned r = x.v + 0x7FFFu + ((x.v >> 16) & 1u);
  return (u16)(r >> 16);
}

#define MFMA16(a, b, c) __builtin_amdgcn_mfma_f32_16x16x32_bf16((a), (b), (c), 0, 0, 0)

// ---------------------------------------------------------------------------
// Dtype probe (R5-verified: inputs are fp32; probe kept for robustness).
// ---------------------------------------------------------------------------
__global__ __launch_bounds__(256) void detect_dtype(const unsigned* __restrict__ x,
                                                    int* __restrict__ flag) {
  __shared__ int cnt;
  if (threadIdx.x == 0) cnt = 0;
  __syncthreads();
  int local = 0;
  for (int i = threadIdx.x; i < 2048; i += 256) {
    unsigned w = x[i];
    int e = (w >> 7) & 0xFF;
    if (e >= 118 && e <= 130) local++;
  }
  atomicAdd(&cnt, local);
  __syncthreads();
  if (threadIdx.x == 0) *flag = (cnt > 1024) ? 1 : 0;
}

__global__ __launch_bounds__(256) void cvt_bf16(const void* __restrict__ src,
                                                u16* __restrict__ dst, int n8,
                                                const int* __restrict__ flag) {
  int i = blockIdx.x * 256 + threadIdx.x;
  if (i >= n8) return;
  if (*flag) {
    ((ulonglong2*)dst)[i] = ((const ulonglong2*)src)[i];
  } else {
    const float* s = (const float*)src + (size_t)i * 8;
    u16 v[8];
#pragma unroll
    for (int j = 0; j < 8; ++j) v[j] = f2bf(s[j]);
    *(ulonglong2*)(dst + (size_t)i * 8) = *(ulonglong2*)v;
  }
}

// cos+sin tables converted in one launch (two tiny launches fused). [R4-verified]
__global__ __launch_bounds__(256) void cvt_bf16_2(const void* __restrict__ src0,
                                                  const void* __restrict__ src1,
                                                  u16* __restrict__ dst0,
                                                  u16* __restrict__ dst1, int n8,
                                                  const int* __restrict__ flag) {
  int half = gridDim.x >> 1;
  const void* src = (blockIdx.x < half) ? src0 : src1;
  u16* dst = (blockIdx.x < half) ? dst0 : dst1;
  int i = (blockIdx.x < half ? blockIdx.x : blockIdx.x - half) * 256 + threadIdx.x;
  if (i >= n8) return;
  if (*flag) {
    ((ulonglong2*)dst)[i] = ((const ulonglong2*)src)[i];
  } else {
    const float* s = (const float*)src + (size_t)i * 8;
    u16 v[8];
#pragma unroll
    for (int j = 0; j < 8; ++j) v[j] = f2bf(s[j]);
    *(ulonglong2*)(dst + (size_t)i * 8) = *(ulonglong2*)v;
  }
}

// ---------------------------------------------------------------------------
// C[M][N] = A[M][K] @ B[N][K]^T, bf16, fp32 accum. m97 structure — R4-exact.
// SESSION LOG (do not re-attempt without new evidence):
//  - R2/R3: 256^2 counted-vmcnt 8-phase rewrite -> intermittent replay race.
//  - R5: RoPE-fused epilogue -> absmax 0.173, unlocatable after 3 audits.
//  - R6: XCD swizzle -> FETCH +35%, dur +2.5us (inputs L3-resident; m160).
//  - R7: LDS XOR bank fix -> conflicts 6.29M->0 but dur UNCHANGED (T2 null
//    in 2-phase regime, m252: conflicts hidden under stage+barrier drain)
//    AND absmax moved 0.0156->0.057 unexplained. Reverted.
// ---------------------------------------------------------------------------
__global__ __launch_bounds__(256) void gemm_bt(const u16* __restrict__ A,
                                               const u16* __restrict__ B,
                                               u16* __restrict__ C,
                                               int M, int N, int K) {
  __shared__ __align__(16) u16 As[128 * 32];
  __shared__ __align__(16) u16 Bs[128 * 32];
  const int m0 = blockIdx.x * 128, n0 = blockIdx.y * 128;
  const int t = threadIdx.x, wave = t >> 6, lane = t & 63;
  const int l15 = lane & 15, quad = lane >> 4;
  const int wm = (wave >> 1) * 64, wn = (wave & 1) * 64;

  f32x4 acc[4][4];
#pragma unroll
  for (int i = 0; i < 4; ++i)
#pragma unroll
    for (int j = 0; j < 4; ++j) acc[i][j] = (f32x4)(0.0f);

  for (int k0 = 0; k0 < K; k0 += 32) {
    __syncthreads();
#pragma unroll
    for (int p = 0; p < 2; ++p) {
      int slot = p * 256 + t;
      int r = slot >> 2, kk = (slot & 3) << 3;
      GLOAD_LDS(A + (size_t)(m0 + r) * K + k0 + kk, As + slot * 8);
      GLOAD_LDS(B + (size_t)(n0 + r) * K + k0 + kk, Bs + slot * 8);
    }
    __syncthreads();
    bf16x8 af[4], bfr[4];
#pragma unroll
    for (int i = 0; i < 4; ++i)
      af[i] = *(const bf16x8*)&As[(wm + i * 16 + l15) * 32 + quad * 8];
#pragma unroll
    for (int j = 0; j < 4; ++j)
      bfr[j] = *(const bf16x8*)&Bs[(wn + j * 16 + l15) * 32 + quad * 8];
#pragma unroll
    for (int i = 0; i < 4; ++i)
#pragma unroll
      for (int j = 0; j < 4; ++j) acc[i][j] = MFMA16(af[i], bfr[j], acc[i][j]);
  }
#pragma unroll
  for (int i = 0; i < 4; ++i)
#pragma unroll
    for (int j = 0; j < 4; ++j)
#pragma unroll
      for (int r = 0; r < 4; ++r) {
        int row = m0 + wm + i * 16 + quad * 4 + r;
        int col = n0 + wn + j * 16 + l15;
        C[(size_t)row * N + col] = f2bf(acc[i][j][r]);
      }
}

// Final projection GEMM with dtype-flagged store to d_out. R4-exact.
__global__ __launch_bounds__(256) void gemm_bt_out(const u16* __restrict__ A,
                                                   const u16* __restrict__ B,
                                                   void* __restrict__ C,
                                                   int M, int N, int K,
                                                   const int* __restrict__ flag) {
  __shared__ __align__(16) u16 As[128 * 32];
  __shared__ __align__(16) u16 Bs[128 * 32];
  const int m0 = blockIdx.x * 128, n0 = blockIdx.y * 128;
  const int t = threadIdx.x, wave = t >> 6, lane = t & 63;
  const int l15 = lane & 15, quad = lane >> 4;
  const int wm = (wave >> 1) * 64, wn = (wave & 1) * 64;
  const int f = *flag;

  f32x4 acc[4][4];
#pragma unroll
  for (int i = 0; i < 4; ++i)
#pragma unroll
    for (int j = 0; j < 4; ++j) acc[i][j] = (f32x4)(0.0f);

  for (int k0 = 0; k0 < K; k0 += 32) {
    __syncthreads();
#pragma unroll
    for (int p = 0; p < 2; ++p) {
      int slot = p * 256 + t;
      int r = slot >> 2, kk = (slot & 3) << 3;
      GLOAD_LDS(A + (size_t)(m0 + r) * K + k0 + kk, As + slot * 8);
      GLOAD_LDS(B + (size_t)(n0 + r) * K + k0 + kk, Bs + slot * 8);
    }
    __syncthreads();
    bf16x8 af[4], bfr[4];
#pragma unroll
    for (int i = 0; i < 4; ++i)
      af[i] = *(const bf16x8*)&As[(wm + i * 16 + l15) * 32 + quad * 8];
#pragma unroll
    for (int j = 0; j < 4; ++j)
      bfr[j] = *(const bf16x8*)&Bs[(wn + j * 16 + l15) * 32 + quad * 8];
#pragma unroll
    for (int i = 0; i < 4; ++i)
#pragma unroll
      for (int j = 0; j < 4; ++j) acc[i][j] = MFMA16(af[i], bfr[j], acc[i][j]);
  }
#pragma unroll
  for (int i = 0; i < 4; ++i)
#pragma unroll
    for (int j = 0; j < 4; ++j)
#pragma unroll
      for (int r = 0; r < 4; ++r) {
        int row = m0 + wm + i * 16 + quad * 4 + r;
        int col = n0 + wn + j * 16 + l15;
        size_t idx = (size_t)row * N + col;
        if (f) ((u16*)C)[idx] = f2bf(acc[i][j][r]);
        else   ((float*)C)[idx] = acc[i][j][r];
      }
}

// ---------------------------------------------------------------------------
// Weight transpose v2 — G13 vectorized. Old version: scalar loads + 2B/lane
// stores. New: 16B/lane loads (ulonglong2 bf16 / 2x float4 fp32), LDS tile
// stride 68 (u64-aligned for all (r, 8-col) offsets; transpose-read dword
// stride 34 mod 32 = 2 -> 2-way = free), 16B/lane packed stores.
// Semantics identical: dst[(c0+c)*dst_ld + r0+r] = cvt(src[(r0+r)*src_ld+c0+c]).
// ---------------------------------------------------------------------------
__global__ __launch_bounds__(256) void transpose_any(const void* __restrict__ src,
                                                     u16* __restrict__ dst,
                                                     int src_ld, int dst_ld,
                                                     const int* __restrict__ flag) {
  __shared__ u16 tile[64 * 68];
  const int c0 = blockIdx.x * 64, r0 = blockIdx.y * 64;
  const int f = *flag;
#pragma unroll
  for (int it = 0; it < 2; ++it) {
    int idx = it * 256 + threadIdx.x;
    int r = idx >> 3, cw = idx & 7;
    union { u16 w[8]; u64 d[2]; } tmp;
    if (f) {
      const u16* sp = (const u16*)src + (size_t)(r0 + r) * src_ld + c0 + cw * 8;
      ulonglong2 v = *(const ulonglong2*)sp;
      tmp.d[0] = v.x; tmp.d[1] = v.y;
    } else {
      const float* sp = (const float*)src + (size_t)(r0 + r) * src_ld + c0 + cw * 8;
      float4 a = *(const float4*)sp;
      float4 b = *(const float4*)(sp + 4);
      tmp.w[0] = f2bf(a.x); tmp.w[1] = f2bf(a.y); tmp.w[2] = f2bf(a.z); tmp.w[3] = f2bf(a.w);
      tmp.w[4] = f2bf(b.x); tmp.w[5] = f2bf(b.y); tmp.w[6] = f2bf(b.z); tmp.w[7] = f2bf(b.w);
    }
    *(u64*)&tile[r * 68 + cw * 8] = tmp.d[0];
    *(u64*)&tile[r * 68 + cw * 8 + 4] = tmp.d[1];
  }
  __syncthreads();
#pragma unroll
  for (int it = 0; it < 2; ++it) {
    int idx = it * 256 + threadIdx.x;
    int c = idx >> 3, rw = idx & 7;
    union { u16 w[8]; u64 d[2]; } o;
#pragma unroll
    for (int j = 0; j < 8; ++j) o.w[j] = tile[(rw * 8 + j) * 68 + c];
    ulonglong2 v; v.x = o.d[0]; v.y = o.d[1];
    *(ulonglong2*)(dst + (size_t)(c0 + c) * dst_ld + r0 + rw * 8) = v;
  }
}

// ---------------------------------------------------------------------------
// Fused RoPE + V-transpose, one launch. Blocks [0,4096): in-place RoPE on
// Cqkv row bid (Q scaled by HD^-0.5*log2(e); attention runs in exp2 domain),
// 16B/lane: 4 rotation pairs per load, u64 trig-table loads. Blocks
// [4096,4608): V-transpose tile (vectorized like transpose_any). Safe merge:
// RoPE touches Cqkv cols [0,2560), V-transpose reads cols [2560,3072) —
// disjoint; no inter-part ordering needed.
// [R5 lesson: the GEMM-epilogue rope fusion failed; THIS keeps rope's exact
// per-element math, only widening the memory access.]
// ---------------------------------------------------------------------------
__global__ __launch_bounds__(256) void rope_vt(u16* __restrict__ Cqkv,
                                               const u16* __restrict__ cosT,
                                               const u16* __restrict__ sinT,
                                               u16* __restrict__ Vt) {
  __shared__ u16 tile[64 * 68];
  const int bid = blockIdx.x;
  const int p = threadIdx.x;
  if (bid < 4096) {
    const float SCALE = 0.12751742f;  // 128^-0.5 * log2(e)
    const int s = bid & 2047;
    u16* row = Cqkv + (size_t)bid * 3072;
    const int i0 = 4 * (p & 15);  // pair base within head: ((col&127)>>1)
    u64 cw4 = *(const u64*)(cosT + s * 64 + i0);
    u64 sw4 = *(const u64*)(sinT + s * 64 + i0);
    float cc[4], ss[4];
#pragma unroll
    for (int k = 0; k < 4; ++k) {
      cc[k] = bf2f((u16)(cw4 >> (16 * k)));
      ss[k] = bf2f((u16)(sw4 >> (16 * k)));
    }
    // Q chunks: all 256 threads, col = p*8 in [0,2048)
    {
      union { bf16x8 v; u64 d[2]; u16 w[8]; } x, o;
      x.v = *(const bf16x8*)(row + p * 8);
#pragma unroll
      for (int k = 0; k < 4; ++k) {
        float x1 = bf2f(x.w[2 * k]), x2 = bf2f(x.w[2 * k + 1]);
        o.w[2 * k]     = f2bf((x1 * cc[k] - x2 * ss[k]) * SCALE);
        o.w[2 * k + 1] = f2bf((x1 * ss[k] + x2 * cc[k]) * SCALE);
      }
      *(bf16x8*)(row + p * 8) = o.v;
    }
    // K chunks: threads < 64, col = 2048 + p*8 in [2048,2560)
    if (p < 64) {
      union { bf16x8 v; u64 d[2]; u16 w[8]; } x, o;
      x.v = *(const bf16x8*)(row + 2048 + p * 8);
#pragma unroll
      for (int k = 0; k < 4; ++k) {
        float x1 = bf2f(x.w[2 * k]), x2 = bf2f(x.w[2 * k + 1]);
        o.w[2 * k]     = f2bf(x1 * cc[k] - x2 * ss[k]);
        o.w[2 * k + 1] = f2bf(x1 * ss[k] + x2 * cc[k]);
      }
      *(bf16x8*)(row + 2048 + p * 8) = o.v;
    }
  } else {
    const int vid = bid - 4096;             // [0,512) <- grid (32,2,8) flattened
    const int s0 = (vid & 31) * 64;
    const int d0 = ((vid >> 5) & 1) * 64;
    const int z = vid >> 6;
    const int b = z >> 2, kvh = z & 3;
    const u16* src = Cqkv + (size_t)b * 2048 * 3072 + 2560 + kvh * 128;
    u16* dst = Vt + (size_t)z * 128 * 2048;
#pragma unroll
    for (int it = 0; it < 2; ++it) {
      int idx = it * 256 + p;
      int r = idx >> 3, cw = idx & 7;
      union { bf16x8 v; u64 d[2]; } x;
      x.v = *(const bf16x8*)(src + (size_t)(s0 + r) * 3072 + d0 + cw * 8);
      *(u64*)&tile[r * 68 + cw * 8] = x.d[0];
      *(u64*)&tile[r * 68 + cw * 8 + 4] = x.d[1];
    }
    __syncthreads();
#pragma unroll
    for (int it = 0; it < 2; ++it) {
      int idx = it * 256 + p;
      int c = idx >> 3, rw = idx & 7;
      union { u16 w[8]; u64 d[2]; } o;
#pragma unroll
      for (int j = 0; j < 8; ++j) o.w[j] = tile[(rw * 8 + j) * 68 + c];
      ulonglong2 v; v.x = o.d[0]; v.y = o.d[1];
      *(ulonglong2*)(dst + (size_t)(d0 + c) * 2048 + s0 + rw * 8) = v;
    }
  }
}

// ---------------------------------------------------------------------------
// Flash attention v6: one q-tile per block, 4 blocks/CU + T5 setprio
// (verified R4). Q arrives pre-scaled; attention runs in exp2 domain.
// ---------------------------------------------------------------------------
__global__ __launch_bounds__(256, 4) void attn(const u16* __restrict__ Cqkv,
                                               const u16* __restrict__ Vt,
                                               u16* __restrict__ O) {
  __shared__ __align__(16) u16 lds[2 * 4096 + 2 * 4096 + 4 * 640];
  const float NEGI = -1e30f;
  const int pair = blockIdx.x, h = blockIdx.y, z = blockIdx.z;
  const int b = z >> 1, ph = z & 1;
  const int kvh = h >> 2;
  const int t = threadIdx.x, wave = t >> 6, lane = t & 63;
  const int l15 = lane & 15, quad = lane >> 4;
  const int krow0 = b * 2048;
  const size_t vbase = ((size_t)b * 4 + kvh) * 128 * 2048;
  const u16* Kg = Cqkv + 2048 + kvh * 128;
  const u16* Qg = Cqkv + h * 128;
  u16* KsB = lds;                       // [2][32*128]
  u16* VsB = lds + 8192;                // [2][128*32]
  u16* PsW = lds + 16384 + wave * 640;  // 16 rows x stride 40
  u16* OsW = lds + wave * 2176;         // epilogue only: 16 rows x stride 136

  const int qt = ph ? (31 - pair) : pair;       // 64-row q tile, 0..31
  const int qrow0 = b * 2048 + qt * 64;         // global row base
  const int q0w = qt * 64 + wave * 16;          // wave's q range start (seq)
  const int myq = q0w + l15;                    // this lane's q (seq)

  // Q fragments -> registers (one row per lane, 4 chunks of 16B)
  bf16x8 qreg[4];
#pragma unroll
  for (int ks = 0; ks < 4; ++ks)
    qreg[ks] = *(const bf16x8*)(Qg + (size_t)(qrow0 + wave * 16 + l15) * 3072 +
                                ks * 32 + quad * 8);
  // prefetch kv tile 0 into buf 0
#pragma unroll
  for (int p = 0; p < 2; ++p) {
    int slot = p * 256 + t;
    int r = slot >> 4;
    int ch = (slot & 15) ^ (r & 15);
    GLOAD_LDS(Kg + (size_t)(krow0 + r) * 3072 + ch * 8, KsB + slot * 8);
  }
#pragma unroll
  for (int p = 0; p < 2; ++p) {
    int slot = p * 256 + t;
    int vr = slot >> 2;
    int vc = ((slot & 3) ^ ((vr >> 1) & 3)) << 3;
    GLOAD_LDS(Vt + vbase + (size_t)vr * 2048 + vc, VsB + slot * 8);
  }

  float l_lane = 0.f;  // this lane's partial sum over its 8 kv per tile
  f32x4 oacc[8];
#pragma unroll
  for (int jd = 0; jd < 8; ++jd) oacc[jd] = (f32x4)(0.0f);

  const int nt = 2 * (qt + 1);
  for (int it = 0; it < nt; ++it) {
    const int k0 = it * 32;
    __syncthreads();  // drains prefetch of tile it; signals buf (it+1)&1 free
    if (it + 1 < nt) {
      const int kn = k0 + 32;
      u16* kb = KsB + ((it + 1) & 1) * 4096;
      u16* vb = VsB + ((it + 1) & 1) * 4096;
#pragma unroll
      for (int p = 0; p < 2; ++p) {
        int slot = p * 256 + t;
        int r = slot >> 4;
        int ch = (slot & 15) ^ (r & 15);
        GLOAD_LDS(Kg + (size_t)(krow0 + kn + r) * 3072 + ch * 8, kb + slot * 8);
      }
#pragma unroll
      for (int p = 0; p < 2; ++p) {
        int slot = p * 256 + t;
        int vr = slot >> 2;
        int vc = ((slot & 3) ^ ((vr >> 1) & 3)) << 3;
        GLOAD_LDS(Vt + vbase + (size_t)vr * 2048 + kn + vc, vb + slot * 8);
      }
    }
    if (k0 > q0w + 15) continue;  // tile fully masked for this wave

    const u16* kb = KsB + (it & 1) * 4096;
    const u16* vb = VsB + (it & 1) * 4096;
    // S^T = K @ Q^T : rows kv (2x16), cols q (16)
    f32x4 sc[2];
    sc[0] = (f32x4)(0.f); sc[1] = (f32x4)(0.f);
    __builtin_amdgcn_s_setprio(1);
#pragma unroll
    for (int ks = 0; ks < 4; ++ks) {
      int chs = ((ks * 4 + quad) ^ l15) * 8;
      bf16x8 kf0 = *(const bf16x8*)&kb[l15 * 128 + chs];
      bf16x8 kf1 = *(const bf16x8*)&kb[(16 + l15) * 128 + chs];
      sc[0] = MFMA16(kf0, qreg[ks], sc[0]);
      sc[1] = MFMA16(kf1, qreg[ks], sc[1]);
    }
    __builtin_amdgcn_s_setprio(0);
    // causal mask — only diagonal tiles need it (wave-uniform branch)
    if (k0 + 31 > q0w) {
#pragma unroll
      for (int j = 0; j < 2; ++j)
#pragma unroll
        for (int r = 0; r < 4; ++r) {
          int kv = k0 + j * 16 + quad * 4 + r;
          if (kv > myq) sc[j][r] = NEGI;
        }
    }
    // direct exp2 softmax: P = exp2(s); l accumulated from truncated P so
    // normalization matches stored bf16 P exactly.
    u16 pb[8];
#pragma unroll
    for (int j = 0; j < 2; ++j)
#pragma unroll
      for (int r = 0; r < 4; ++r) {
        float pv = __builtin_amdgcn_exp2f(sc[j][r]);
        unsigned bits = __float_as_uint(pv);
        l_lane += __uint_as_float(bits & 0xFFFF0000u);
        pb[j * 4 + r] = (u16)(bits >> 16);
      }
    // P -> Ps[q][kv] (stride 40), 2 x ds_write_b64, then B-frag read (in-wave)
#pragma unroll
    for (int j = 0; j < 2; ++j) {
      u64 pk = (u64)pb[j * 4] | ((u64)pb[j * 4 + 1] << 16) |
               ((u64)pb[j * 4 + 2] << 32) | ((u64)pb[j * 4 + 3] << 48);
      *(u64*)&PsW[l15 * 40 + j * 16 + quad * 4] = pk;
    }
    bf16x8 pf = *(const bf16x8*)&PsW[l15 * 40 + quad * 8];
    // O^T += V^T @ P
    __builtin_amdgcn_s_setprio(1);
#pragma unroll
    for (int jd = 0; jd < 8; ++jd) {
      int d = jd * 16 + l15;
      bf16x8 vf = *(const bf16x8*)&vb[d * 32 + ((quad ^ ((l15 >> 1) & 3)) << 3)];
      oacc[jd] = MFMA16(vf, pf, oacc[jd]);
    }
    __builtin_amdgcn_s_setprio(0);
  }
  __syncthreads();  // all waves done with K/V LDS before Os overlays it

  // final l for this q row: reduce partial sums across the 4 quads
  float l_st = l_lane;
  l_st += __shfl_xor(l_st, 16);
  l_st += __shfl_xor(l_st, 32);
  float inv = 1.0f / l_st;

  // epilogue: O^T -> LDS transpose -> coalesced global O[b*S+q][h*128+d]
#pragma unroll
  for (int jd = 0; jd < 8; ++jd) {
    u64 pk = (u64)f2bf(oacc[jd][0] * inv) | ((u64)f2bf(oacc[jd][1] * inv) << 16) |
             ((u64)f2bf(oacc[jd][2] * inv) << 32) | ((u64)f2bf(oacc[jd][3] * inv) << 48);
    *(u64*)&OsW[l15 * 136 + jd * 16 + quad * 4] = pk;
  }
#pragma unroll
  for (int rr = 0; rr < 4; ++rr) {
    int row = rr * 4 + quad;
    bf16x8 ov = *(const bf16x8*)&OsW[row * 136 + l15 * 8];
    *(bf16x8*)&O[(size_t)(qrow0 + wave * 16 + row) * 2048 + h * 128 + l15 * 8] = ov;
  }
}

// ---------------------------------------------------------------------------
// Workspace plan (55.1 MB peak) — unchanged (verified passing).
// ---------------------------------------------------------------------------
extern "C" void kernel_launch(void* const* d_in, const int* in_sizes, int n_in,
                              void* d_out, int out_size, void* d_ws, size_t ws_size,
                              hipStream_t stream) {
  const void* x    = d_in[0];
  const void* cosI = d_in[2];
  const void* sinI = d_in[3];
  const void* Wq   = d_in[4];
  const void* Wkv  = d_in[5];
  const void* Wo   = d_in[6];

  char* ws = (char*)d_ws;
  u16* Cqkv  = (u16*)ws;
  u16* xb    = (u16*)(ws + 25165824);
  u16* Vt    = (u16*)(ws + 25165824);
  u16* Oreg  = (u16*)(ws + 29360128);
  u16* WqkvT = (u16*)(ws + 41943040);
  u16* cosb  = (u16*)(ws + 54525952);
  u16* sinb  = (u16*)(ws + 54788096);
  int* flag  = (int*)(ws + 55050240);
  u16* WoT   = Cqkv;

  detect_dtype<<<1, 256, 0, stream>>>((const unsigned*)x, flag);
  cvt_bf16<<<4096, 256, 0, stream>>>(x, xb, 1048576, flag);
  cvt_bf16_2<<<128, 256, 0, stream>>>(cosI, sinI, cosb, sinb, 16384, flag);
  transpose_any<<<dim3(32, 32), 256, 0, stream>>>(Wq, WqkvT, 2048, 2048, flag);
  transpose_any<<<dim3(16, 32), 256, 0, stream>>>(Wkv, WqkvT + (size_t)2048 * 2048,
                                                  1024, 2048, flag);
  gemm_bt<<<dim3(32, 24), 256, 0, stream>>>(xb, WqkvT, Cqkv, 4096, 3072, 2048);
  rope_vt<<<4608, 256, 0, stream>>>(Cqkv, cosb, sinb, Vt);
  attn<<<dim3(16, 16, 4), 256, 0, stream>>>(Cqkv, Vt, Oreg);
  transpose_any<<<dim3(32, 32), 256, 0, stream>>>(Wo, WoT, 2048, 2048, flag);
  gemm_bt_out<<<dim3(32, 16), 256, 0, stream>>>(Oreg, WoT, d_out, 4096, 2048, 2048, flag);
}

// Round 9
// 318.625 us; speedup vs baseline: 1.1401x; 1.0512x over previous
//
#include <hip/hip_runtime.h>

typedef unsigned short u16;
typedef unsigned long long u64;
typedef __attribute__((ext_vector_type(8))) short bf16x8;
typedef __attribute__((ext_vector_type(4))) float f32x4;

// async global->LDS, 16B per lane. LDS dest must be wave-uniform base + lane*16.
#define GLOAD_LDS(gptr, lptr)                                                            \
  __builtin_amdgcn_global_load_lds(                                                      \
      (const __attribute__((address_space(1))) unsigned int*)(gptr),                     \
      (__attribute__((address_space(3))) unsigned int*)(lptr), 16, 0, 0)

__device__ __forceinline__ float bf2f(u16 u) {
  union { unsigned v; float f; } x; x.v = ((unsigned)u) << 16; return x.f;
}
__device__ __forceinline__ u16 f2bf(float f) {
  union { float f; unsigned v; } x; x.f = f;
  unsigned r = x.v + 0x7FFFu + ((x.v >> 16) & 1u);
  return (u16)(r >> 16);
}

#define MFMA16(a, b, c) __builtin_amdgcn_mfma_f32_16x16x32_bf16((a), (b), (c), 0, 0, 0)

// ---------------------------------------------------------------------------
// Dtype probe (R5-verified: inputs are fp32; probe kept for robustness).
// ---------------------------------------------------------------------------
__global__ __launch_bounds__(256) void detect_dtype(const unsigned* __restrict__ x,
                                                    int* __restrict__ flag) {
  __shared__ int cnt;
  if (threadIdx.x == 0) cnt = 0;
  __syncthreads();
  int local = 0;
  for (int i = threadIdx.x; i < 2048; i += 256) {
    unsigned w = x[i];
    int e = (w >> 7) & 0xFF;
    if (e >= 118 && e <= 130) local++;
  }
  atomicAdd(&cnt, local);
  __syncthreads();
  if (threadIdx.x == 0) *flag = (cnt > 1024) ? 1 : 0;
}

__global__ __launch_bounds__(256) void cvt_bf16(const void* __restrict__ src,
                                                u16* __restrict__ dst, int n8,
                                                const int* __restrict__ flag) {
  int i = blockIdx.x * 256 + threadIdx.x;
  if (i >= n8) return;
  if (*flag) {
    ((ulonglong2*)dst)[i] = ((const ulonglong2*)src)[i];
  } else {
    const float* s = (const float*)src + (size_t)i * 8;
    u16 v[8];
#pragma unroll
    for (int j = 0; j < 8; ++j) v[j] = f2bf(s[j]);
    *(ulonglong2*)(dst + (size_t)i * 8) = *(ulonglong2*)v;
  }
}

// cos+sin tables converted in one launch (two tiny launches fused). [R4-verified]
__global__ __launch_bounds__(256) void cvt_bf16_2(const void* __restrict__ src0,
                                                  const void* __restrict__ src1,
                                                  u16* __restrict__ dst0,
                                                  u16* __restrict__ dst1, int n8,
                                                  const int* __restrict__ flag) {
  int half = gridDim.x >> 1;
  const void* src = (blockIdx.x < half) ? src0 : src1;
  u16* dst = (blockIdx.x < half) ? dst0 : dst1;
  int i = (blockIdx.x < half ? blockIdx.x : blockIdx.x - half) * 256 + threadIdx.x;
  if (i >= n8) return;
  if (*flag) {
    ((ulonglong2*)dst)[i] = ((const ulonglong2*)src)[i];
  } else {
    const float* s = (const float*)src + (size_t)i * 8;
    u16 v[8];
#pragma unroll
    for (int j = 0; j < 8; ++j) v[j] = f2bf(s[j]);
    *(ulonglong2*)(dst + (size_t)i * 8) = *(ulonglong2*)v;
  }
}

// ---------------------------------------------------------------------------
// C[M][N] = A[M][K] @ B[N][K]^T, bf16, fp32 accum. m97 structure, BK=64.
// R9 change: double the K-step from 32 to 64 with LDS as TWO [128][32]
// sub-tiles per matrix ([2][128][32], 32KB total). Halves the number of
// __syncthreads barrier pairs (128 -> 64); the ~20% per-barrier
// vmcnt(0)+lgkmcnt(0) drain (composed-model) amortizes over 2x the MFMA.
// Sync structure UNCHANGED (2x __syncthreads per iter, no counted vmcnt —
// the R2/R3 failure surface is untouched). Per-sub-tile staging map and
// frag addressing identical to the verified BK=32 kernel; accumulation
// order (k0 then k0+32) bit-identical. LDS 32KB -> 5 blocks/CU by LDS;
// occupancy stays grid-limited at 3 blocks/CU (m132's BK=128 regression
// was the 64KB occupancy cut; BK=64 avoids it).
// SESSION LOG (do not re-attempt without new evidence):
//  - R2/R3: 256^2 counted-vmcnt 8-phase rewrite -> intermittent replay race.
//  - R5: RoPE-fused epilogue -> absmax 0.173, unlocatable after 3 audits.
//  - R6: XCD swizzle -> FETCH +35%, dur +2.5us (inputs L3-resident; m160).
//  - R7: LDS XOR bank fix -> conflicts 6.29M->0, dur UNCHANGED (T2 null in
//    2-phase regime, m252) and absmax moved unexplained. Reverted.
// ---------------------------------------------------------------------------
__global__ __launch_bounds__(256) void gemm_bt(const u16* __restrict__ A,
                                               const u16* __restrict__ B,
                                               u16* __restrict__ C,
                                               int M, int N, int K) {
  __shared__ __align__(16) u16 As[2 * 128 * 32];
  __shared__ __align__(16) u16 Bs[2 * 128 * 32];
  const int m0 = blockIdx.x * 128, n0 = blockIdx.y * 128;
  const int t = threadIdx.x, wave = t >> 6, lane = t & 63;
  const int l15 = lane & 15, quad = lane >> 4;
  const int wm = (wave >> 1) * 64, wn = (wave & 1) * 64;

  f32x4 acc[4][4];
#pragma unroll
  for (int i = 0; i < 4; ++i)
#pragma unroll
    for (int j = 0; j < 4; ++j) acc[i][j] = (f32x4)(0.0f);

  for (int k0 = 0; k0 < K; k0 += 64) {
    __syncthreads();
#pragma unroll
    for (int p = 0; p < 2; ++p) {
      int slot = p * 256 + t;
      int r = slot >> 2, kk = (slot & 3) << 3;
      GLOAD_LDS(A + (size_t)(m0 + r) * K + k0 + kk, As + slot * 8);
      GLOAD_LDS(B + (size_t)(n0 + r) * K + k0 + kk, Bs + slot * 8);
      GLOAD_LDS(A + (size_t)(m0 + r) * K + k0 + 32 + kk, As + 4096 + slot * 8);
      GLOAD_LDS(B + (size_t)(n0 + r) * K + k0 + 32 + kk, Bs + 4096 + slot * 8);
    }
    __syncthreads();
#pragma unroll
    for (int s = 0; s < 2; ++s) {
      bf16x8 af[4], bfr[4];
#pragma unroll
      for (int i = 0; i < 4; ++i)
        af[i] = *(const bf16x8*)&As[s * 4096 + (wm + i * 16 + l15) * 32 + quad * 8];
#pragma unroll
      for (int j = 0; j < 4; ++j)
        bfr[j] = *(const bf16x8*)&Bs[s * 4096 + (wn + j * 16 + l15) * 32 + quad * 8];
#pragma unroll
      for (int i = 0; i < 4; ++i)
#pragma unroll
        for (int j = 0; j < 4; ++j) acc[i][j] = MFMA16(af[i], bfr[j], acc[i][j]);
    }
  }
#pragma unroll
  for (int i = 0; i < 4; ++i)
#pragma unroll
    for (int j = 0; j < 4; ++j)
#pragma unroll
      for (int r = 0; r < 4; ++r) {
        int row = m0 + wm + i * 16 + quad * 4 + r;
        int col = n0 + wn + j * 16 + l15;
        C[(size_t)row * N + col] = f2bf(acc[i][j][r]);
      }
}

// Final projection GEMM with dtype-flagged store to d_out. Same BK=64 change.
__global__ __launch_bounds__(256) void gemm_bt_out(const u16* __restrict__ A,
                                                   const u16* __restrict__ B,
                                                   void* __restrict__ C,
                                                   int M, int N, int K,
                                                   const int* __restrict__ flag) {
  __shared__ __align__(16) u16 As[2 * 128 * 32];
  __shared__ __align__(16) u16 Bs[2 * 128 * 32];
  const int m0 = blockIdx.x * 128, n0 = blockIdx.y * 128;
  const int t = threadIdx.x, wave = t >> 6, lane = t & 63;
  const int l15 = lane & 15, quad = lane >> 4;
  const int wm = (wave >> 1) * 64, wn = (wave & 1) * 64;
  const int f = *flag;

  f32x4 acc[4][4];
#pragma unroll
  for (int i = 0; i < 4; ++i)
#pragma unroll
    for (int j = 0; j < 4; ++j) acc[i][j] = (f32x4)(0.0f);

  for (int k0 = 0; k0 < K; k0 += 64) {
    __syncthreads();
#pragma unroll
    for (int p = 0; p < 2; ++p) {
      int slot = p * 256 + t;
      int r = slot >> 2, kk = (slot & 3) << 3;
      GLOAD_LDS(A + (size_t)(m0 + r) * K + k0 + kk, As + slot * 8);
      GLOAD_LDS(B + (size_t)(n0 + r) * K + k0 + kk, Bs + slot * 8);
      GLOAD_LDS(A + (size_t)(m0 + r) * K + k0 + 32 + kk, As + 4096 + slot * 8);
      GLOAD_LDS(B + (size_t)(n0 + r) * K + k0 + 32 + kk, Bs + 4096 + slot * 8);
    }
    __syncthreads();
#pragma unroll
    for (int s = 0; s < 2; ++s) {
      bf16x8 af[4], bfr[4];
#pragma unroll
      for (int i = 0; i < 4; ++i)
        af[i] = *(const bf16x8*)&As[s * 4096 + (wm + i * 16 + l15) * 32 + quad * 8];
#pragma unroll
      for (int j = 0; j < 4; ++j)
        bfr[j] = *(const bf16x8*)&Bs[s * 4096 + (wn + j * 16 + l15) * 32 + quad * 8];
#pragma unroll
      for (int i = 0; i < 4; ++i)
#pragma unroll
        for (int j = 0; j < 4; ++j) acc[i][j] = MFMA16(af[i], bfr[j], acc[i][j]);
    }
  }
#pragma unroll
  for (int i = 0; i < 4; ++i)
#pragma unroll
    for (int j = 0; j < 4; ++j)
#pragma unroll
      for (int r = 0; r < 4; ++r) {
        int row = m0 + wm + i * 16 + quad * 4 + r;
        int col = n0 + wn + j * 16 + l15;
        size_t idx = (size_t)row * N + col;
        if (f) ((u16*)C)[idx] = f2bf(acc[i][j][r]);
        else   ((float*)C)[idx] = acc[i][j][r];
      }
}

// ---------------------------------------------------------------------------
// Weight transpose v2 — G13 vectorized (R8-verified). 16B/lane loads, LDS
// tile stride 68, 16B/lane packed stores.
// ---------------------------------------------------------------------------
__global__ __launch_bounds__(256) void transpose_any(const void* __restrict__ src,
                                                     u16* __restrict__ dst,
                                                     int src_ld, int dst_ld,
                                                     const int* __restrict__ flag) {
  __shared__ u16 tile[64 * 68];
  const int c0 = blockIdx.x * 64, r0 = blockIdx.y * 64;
  const int f = *flag;
#pragma unroll
  for (int it = 0; it < 2; ++it) {
    int idx = it * 256 + threadIdx.x;
    int r = idx >> 3, cw = idx & 7;
    union { u16 w[8]; u64 d[2]; } tmp;
    if (f) {
      const u16* sp = (const u16*)src + (size_t)(r0 + r) * src_ld + c0 + cw * 8;
      ulonglong2 v = *(const ulonglong2*)sp;
      tmp.d[0] = v.x; tmp.d[1] = v.y;
    } else {
      const float* sp = (const float*)src + (size_t)(r0 + r) * src_ld + c0 + cw * 8;
      float4 a = *(const float4*)sp;
      float4 b = *(const float4*)(sp + 4);
      tmp.w[0] = f2bf(a.x); tmp.w[1] = f2bf(a.y); tmp.w[2] = f2bf(a.z); tmp.w[3] = f2bf(a.w);
      tmp.w[4] = f2bf(b.x); tmp.w[5] = f2bf(b.y); tmp.w[6] = f2bf(b.z); tmp.w[7] = f2bf(b.w);
    }
    *(u64*)&tile[r * 68 + cw * 8] = tmp.d[0];
    *(u64*)&tile[r * 68 + cw * 8 + 4] = tmp.d[1];
  }
  __syncthreads();
#pragma unroll
  for (int it = 0; it < 2; ++it) {
    int idx = it * 256 + threadIdx.x;
    int c = idx >> 3, rw = idx & 7;
    union { u16 w[8]; u64 d[2]; } o;
#pragma unroll
    for (int j = 0; j < 8; ++j) o.w[j] = tile[(rw * 8 + j) * 68 + c];
    ulonglong2 v; v.x = o.d[0]; v.y = o.d[1];
    *(ulonglong2*)(dst + (size_t)(c0 + c) * dst_ld + r0 + rw * 8) = v;
  }
}

// ---------------------------------------------------------------------------
// Fused RoPE + V-transpose, one launch (R8-verified). Blocks [0,4096):
// in-place vectorized RoPE on Cqkv cols [0,2560). Blocks [4096,4608):
// vectorized V-transpose of cols [2560,3072) — disjoint, race-free.
// ---------------------------------------------------------------------------
__global__ __launch_bounds__(256) void rope_vt(u16* __restrict__ Cqkv,
                                               const u16* __restrict__ cosT,
                                               const u16* __restrict__ sinT,
                                               u16* __restrict__ Vt) {
  __shared__ u16 tile[64 * 68];
  const int bid = blockIdx.x;
  const int p = threadIdx.x;
  if (bid < 4096) {
    const float SCALE = 0.12751742f;  // 128^-0.5 * log2(e)
    const int s = bid & 2047;
    u16* row = Cqkv + (size_t)bid * 3072;
    const int i0 = 4 * (p & 15);  // pair base within head: ((col&127)>>1)
    u64 cw4 = *(const u64*)(cosT + s * 64 + i0);
    u64 sw4 = *(const u64*)(sinT + s * 64 + i0);
    float cc[4], ss[4];
#pragma unroll
    for (int k = 0; k < 4; ++k) {
      cc[k] = bf2f((u16)(cw4 >> (16 * k)));
      ss[k] = bf2f((u16)(sw4 >> (16 * k)));
    }
    // Q chunks: all 256 threads, col = p*8 in [0,2048)
    {
      union { bf16x8 v; u64 d[2]; u16 w[8]; } x, o;
      x.v = *(const bf16x8*)(row + p * 8);
#pragma unroll
      for (int k = 0; k < 4; ++k) {
        float x1 = bf2f(x.w[2 * k]), x2 = bf2f(x.w[2 * k + 1]);
        o.w[2 * k]     = f2bf((x1 * cc[k] - x2 * ss[k]) * SCALE);
        o.w[2 * k + 1] = f2bf((x1 * ss[k] + x2 * cc[k]) * SCALE);
      }
      *(bf16x8*)(row + p * 8) = o.v;
    }
    // K chunks: threads < 64, col = 2048 + p*8 in [2048,2560)
    if (p < 64) {
      union { bf16x8 v; u64 d[2]; u16 w[8]; } x, o;
      x.v = *(const bf16x8*)(row + 2048 + p * 8);
#pragma unroll
      for (int k = 0; k < 4; ++k) {
        float x1 = bf2f(x.w[2 * k]), x2 = bf2f(x.w[2 * k + 1]);
        o.w[2 * k]     = f2bf(x1 * cc[k] - x2 * ss[k]);
        o.w[2 * k + 1] = f2bf(x1 * ss[k] + x2 * cc[k]);
      }
      *(bf16x8*)(row + 2048 + p * 8) = o.v;
    }
  } else {
    const int vid = bid - 4096;             // [0,512) <- grid (32,2,8) flattened
    const int s0 = (vid & 31) * 64;
    const int d0 = ((vid >> 5) & 1) * 64;
    const int z = vid >> 6;
    const int b = z >> 2, kvh = z & 3;
    const u16* src = Cqkv + (size_t)b * 2048 * 3072 + 2560 + kvh * 128;
    u16* dst = Vt + (size_t)z * 128 * 2048;
#pragma unroll
    for (int it = 0; it < 2; ++it) {
      int idx = it * 256 + p;
      int r = idx >> 3, cw = idx & 7;
      union { bf16x8 v; u64 d[2]; } x;
      x.v = *(const bf16x8*)(src + (size_t)(s0 + r) * 3072 + d0 + cw * 8);
      *(u64*)&tile[r * 68 + cw * 8] = x.d[0];
      *(u64*)&tile[r * 68 + cw * 8 + 4] = x.d[1];
    }
    __syncthreads();
#pragma unroll
    for (int it = 0; it < 2; ++it) {
      int idx = it * 256 + p;
      int c = idx >> 3, rw = idx & 7;
      union { u16 w[8]; u64 d[2]; } o;
#pragma unroll
      for (int j = 0; j < 8; ++j) o.w[j] = tile[(rw * 8 + j) * 68 + c];
      ulonglong2 v; v.x = o.d[0]; v.y = o.d[1];
      *(ulonglong2*)(dst + (size_t)(d0 + c) * 2048 + s0 + rw * 8) = v;
    }
  }
}

// ---------------------------------------------------------------------------
// Flash attention v6: one q-tile per block, 4 blocks/CU + T5 setprio
// (verified R4). Q arrives pre-scaled; attention runs in exp2 domain.
// ---------------------------------------------------------------------------
__global__ __launch_bounds__(256, 4) void attn(const u16* __restrict__ Cqkv,
                                               const u16* __restrict__ Vt,
                                               u16* __restrict__ O) {
  __shared__ __align__(16) u16 lds[2 * 4096 + 2 * 4096 + 4 * 640];
  const float NEGI = -1e30f;
  const int pair = blockIdx.x, h = blockIdx.y, z = blockIdx.z;
  const int b = z >> 1, ph = z & 1;
  const int kvh = h >> 2;
  const int t = threadIdx.x, wave = t >> 6, lane = t & 63;
  const int l15 = lane & 15, quad = lane >> 4;
  const int krow0 = b * 2048;
  const size_t vbase = ((size_t)b * 4 + kvh) * 128 * 2048;
  const u16* Kg = Cqkv + 2048 + kvh * 128;
  const u16* Qg = Cqkv + h * 128;
  u16* KsB = lds;                       // [2][32*128]
  u16* VsB = lds + 8192;                // [2][128*32]
  u16* PsW = lds + 16384 + wave * 640;  // 16 rows x stride 40
  u16* OsW = lds + wave * 2176;         // epilogue only: 16 rows x stride 136

  const int qt = ph ? (31 - pair) : pair;       // 64-row q tile, 0..31
  const int qrow0 = b * 2048 + qt * 64;         // global row base
  const int q0w = qt * 64 + wave * 16;          // wave's q range start (seq)
  const int myq = q0w + l15;                    // this lane's q (seq)

  // Q fragments -> registers (one row per lane, 4 chunks of 16B)
  bf16x8 qreg[4];
#pragma unroll
  for (int ks = 0; ks < 4; ++ks)
    qreg[ks] = *(const bf16x8*)(Qg + (size_t)(qrow0 + wave * 16 + l15) * 3072 +
                                ks * 32 + quad * 8);
  // prefetch kv tile 0 into buf 0
#pragma unroll
  for (int p = 0; p < 2; ++p) {
    int slot = p * 256 + t;
    int r = slot >> 4;
    int ch = (slot & 15) ^ (r & 15);
    GLOAD_LDS(Kg + (size_t)(krow0 + r) * 3072 + ch * 8, KsB + slot * 8);
  }
#pragma unroll
  for (int p = 0; p < 2; ++p) {
    int slot = p * 256 + t;
    int vr = slot >> 2;
    int vc = ((slot & 3) ^ ((vr >> 1) & 3)) << 3;
    GLOAD_LDS(Vt + vbase + (size_t)vr * 2048 + vc, VsB + slot * 8);
  }

  float l_lane = 0.f;  // this lane's partial sum over its 8 kv per tile
  f32x4 oacc[8];
#pragma unroll
  for (int jd = 0; jd < 8; ++jd) oacc[jd] = (f32x4)(0.0f);

  const int nt = 2 * (qt + 1);
  for (int it = 0; it < nt; ++it) {
    const int k0 = it * 32;
    __syncthreads();  // drains prefetch of tile it; signals buf (it+1)&1 free
    if (it + 1 < nt) {
      const int kn = k0 + 32;
      u16* kb = KsB + ((it + 1) & 1) * 4096;
      u16* vb = VsB + ((it + 1) & 1) * 4096;
#pragma unroll
      for (int p = 0; p < 2; ++p) {
        int slot = p * 256 + t;
        int r = slot >> 4;
        int ch = (slot & 15) ^ (r & 15);
        GLOAD_LDS(Kg + (size_t)(krow0 + kn + r) * 3072 + ch * 8, kb + slot * 8);
      }
#pragma unroll
      for (int p = 0; p < 2; ++p) {
        int slot = p * 256 + t;
        int vr = slot >> 2;
        int vc = ((slot & 3) ^ ((vr >> 1) & 3)) << 3;
        GLOAD_LDS(Vt + vbase + (size_t)vr * 2048 + kn + vc, vb + slot * 8);
      }
    }
    if (k0 > q0w + 15) continue;  // tile fully masked for this wave

    const u16* kb = KsB + (it & 1) * 4096;
    const u16* vb = VsB + (it & 1) * 4096;
    // S^T = K @ Q^T : rows kv (2x16), cols q (16)
    f32x4 sc[2];
    sc[0] = (f32x4)(0.f); sc[1] = (f32x4)(0.f);
    __builtin_amdgcn_s_setprio(1);
#pragma unroll
    for (int ks = 0; ks < 4; ++ks) {
      int chs = ((ks * 4 + quad) ^ l15) * 8;
      bf16x8 kf0 = *(const bf16x8*)&kb[l15 * 128 + chs];
      bf16x8 kf1 = *(const bf16x8*)&kb[(16 + l15) * 128 + chs];
      sc[0] = MFMA16(kf0, qreg[ks], sc[0]);
      sc[1] = MFMA16(kf1, qreg[ks], sc[1]);
    }
    __builtin_amdgcn_s_setprio(0);
    // causal mask — only diagonal tiles need it (wave-uniform branch)
    if (k0 + 31 > q0w) {
#pragma unroll
      for (int j = 0; j < 2; ++j)
#pragma unroll
        for (int r = 0; r < 4; ++r) {
          int kv = k0 + j * 16 + quad * 4 + r;
          if (kv > myq) sc[j][r] = NEGI;
        }
    }
    // direct exp2 softmax: P = exp2(s); l accumulated from truncated P so
    // normalization matches stored bf16 P exactly.
    u16 pb[8];
#pragma unroll
    for (int j = 0; j < 2; ++j)
#pragma unroll
      for (int r = 0; r < 4; ++r) {
        float pv = __builtin_amdgcn_exp2f(sc[j][r]);
        unsigned bits = __float_as_uint(pv);
        l_lane += __uint_as_float(bits & 0xFFFF0000u);
        pb[j * 4 + r] = (u16)(bits >> 16);
      }
    // P -> Ps[q][kv] (stride 40), 2 x ds_write_b64, then B-frag read (in-wave)
#pragma unroll
    for (int j = 0; j < 2; ++j) {
      u64 pk = (u64)pb[j * 4] | ((u64)pb[j * 4 + 1] << 16) |
               ((u64)pb[j * 4 + 2] << 32) | ((u64)pb[j * 4 + 3] << 48);
      *(u64*)&PsW[l15 * 40 + j * 16 + quad * 4] = pk;
    }
    bf16x8 pf = *(const bf16x8*)&PsW[l15 * 40 + quad * 8];
    // O^T += V^T @ P
    __builtin_amdgcn_s_setprio(1);
#pragma unroll
    for (int jd = 0; jd < 8; ++jd) {
      int d = jd * 16 + l15;
      bf16x8 vf = *(const bf16x8*)&vb[d * 32 + ((quad ^ ((l15 >> 1) & 3)) << 3)];
      oacc[jd] = MFMA16(vf, pf, oacc[jd]);
    }
    __builtin_amdgcn_s_setprio(0);
  }
  __syncthreads();  // all waves done with K/V LDS before Os overlays it

  // final l for this q row: reduce partial sums across the 4 quads
  float l_st = l_lane;
  l_st += __shfl_xor(l_st, 16);
  l_st += __shfl_xor(l_st, 32);
  float inv = 1.0f / l_st;

  // epilogue: O^T -> LDS transpose -> coalesced global O[b*S+q][h*128+d]
#pragma unroll
  for (int jd = 0; jd < 8; ++jd) {
    u64 pk = (u64)f2bf(oacc[jd][0] * inv) | ((u64)f2bf(oacc[jd][1] * inv) << 16) |
             ((u64)f2bf(oacc[jd][2] * inv) << 32) | ((u64)f2bf(oacc[jd][3] * inv) << 48);
    *(u64*)&OsW[l15 * 136 + jd * 16 + quad * 4] = pk;
  }
#pragma unroll
  for (int rr = 0; rr < 4; ++rr) {
    int row = rr * 4 + quad;
    bf16x8 ov = *(const bf16x8*)&OsW[row * 136 + l15 * 8];
    *(bf16x8*)&O[(size_t)(qrow0 + wave * 16 + row) * 2048 + h * 128 + l15 * 8] = ov;
  }
}

// ---------------------------------------------------------------------------
// Workspace plan (55.1 MB peak) — unchanged (verified passing).
// ---------------------------------------------------------------------------
extern "C" void kernel_launch(void* const* d_in, const int* in_sizes, int n_in,
                              void* d_out, int out_size, void* d_ws, size_t ws_size,
                              hipStream_t stream) {
  const void* x    = d_in[0];
  const void* cosI = d_in[2];
  const void* sinI = d_in[3];
  const void* Wq   = d_in[4];
  const void* Wkv  = d_in[5];
  const void* Wo   = d_in[6];

  char* ws = (char*)d_ws;
  u16* Cqkv  = (u16*)ws;
  u16* xb    = (u16*)(ws + 25165824);
  u16* Vt    = (u16*)(ws + 25165824);
  u16* Oreg  = (u16*)(ws + 29360128);
  u16* WqkvT = (u16*)(ws + 41943040);
  u16* cosb  = (u16*)(ws + 54525952);
  u16* sinb  = (u16*)(ws + 54788096);
  int* flag  = (int*)(ws + 55050240);
  u16* WoT   = Cqkv;

  detect_dtype<<<1, 256, 0, stream>>>((const unsigned*)x, flag);
  cvt_bf16<<<4096, 256, 0, stream>>>(x, xb, 1048576, flag);
  cvt_bf16_2<<<128, 256, 0, stream>>>(cosI, sinI, cosb, sinb, 16384, flag);
  transpose_any<<<dim3(32, 32), 256, 0, stream>>>(Wq, WqkvT, 2048, 2048, flag);
  transpose_any<<<dim3(16, 32), 256, 0, stream>>>(Wkv, WqkvT + (size_t)2048 * 2048,
                                                  1024, 2048, flag);
  gemm_bt<<<dim3(32, 24), 256, 0, stream>>>(xb, WqkvT, Cqkv, 4096, 3072, 2048);
  rope_vt<<<4608, 256, 0, stream>>>(Cqkv, cosb, sinb, Vt);
  attn<<<dim3(16, 16, 4), 256, 0, stream>>>(Cqkv, Vt, Oreg);
  transpose_any<<<dim3(32, 32), 256, 0, stream>>>(Wo, WoT, 2048, 2048, flag);
  gemm_bt_out<<<dim3(32, 16), 256, 0, stream>>>(Oreg, WoT, d_out, 4096, 2048, 2048, flag);
}